// Round 7
// baseline (1294.332 us; speedup 1.0000x reference)
//
#include <hip/hip_runtime.h>
#include <hip/hip_bf16.h>
#include <math.h>

// Problem constants
#define Bc   4
#define Tc   6
#define Nc   1024
#define CSc  48
#define GSc  32
#define Hc   270
#define ATc  32
#define DAc  64
#define Ec   32
#define Lc   32
#define EDc  400
#define OUTc 4000
#define H3c  810
#define H4c  1080
#define BEc  128
#define KPE  416    // ED padded
#define KPG  64     // CS padded
#define KAB  320    // Abuf K: 32 co + 270 h + 18 pad
#define NCMB 1382   // combined N: 32 k + 270 v + 270 r + 270 z + 270 in + 270 hn
#define NZCAP 96
#define INV_SQRT_AT_F 0.17677669529663687f

typedef unsigned short ushort_t;
using s8v  = __attribute__((ext_vector_type(8))) short;
using f4v  = __attribute__((ext_vector_type(4))) float;
using u16x8= __attribute__((ext_vector_type(8))) unsigned short;

__device__ __forceinline__ float sigmoid_f(float x){ return 1.0f/(1.0f+expf(-x)); }
__device__ __forceinline__ ushort_t f2bf(float x){
    __hip_bfloat16 b = __float2bfloat16(x);
    return *reinterpret_cast<ushort_t*>(&b);
}
__device__ __forceinline__ float b2f(ushort_t u){
    return __uint_as_float(((unsigned int)u)<<16);
}

// ---------------------------------------------------------------------------
// bf16 MFMA GEMM, 128x128 tile, 4 waves.
// EPIL 0: f32 store (+bias)
// EPIL 1: leaky-relu dual bf16: row<4096 -> Abuf (stride KAB), else no (stride 32)
// EPIL 5: combined kvgi+gh: col<32 kb bf16; col<302 vT bf16 transposed; else gsum f32
// ASEL 2: cono on-the-fly: A=c_emb(f32), P2=n_emb(f32), PF=S, DV=code_x, DV2=neighbors
// ASEL 3: lstm gather: PF=Eemb(f32), DV=events
// ---------------------------------------------------------------------------
template<int EPIL, int SPLITK, int ASEL>
__global__ __launch_bounds__(256)
void mfma_k(const ushort_t* __restrict__ A, const ushort_t* __restrict__ BT,
            const float* __restrict__ bias,
            void* __restrict__ P0, void* __restrict__ P1, void* __restrict__ P2,
            const float* __restrict__ PF, const int* __restrict__ DV,
            const int* __restrict__ DV2,
            int M, int N, int Kp, int lda, int ldb, int ldc,
            long long sA, long long sB, long long sC, int tpar)
{
    __shared__ ushort_t As[128*40];
    __shared__ ushort_t Bs[128*40];
    const int z = blockIdx.z;
    int kbeg = 0, kend = Kp;
    if (SPLITK > 0){
        int ks = Kp / SPLITK;
        kbeg = z*ks; kend = kbeg + ks;
    } else {
        if (ASEL == 0) A += (size_t)z * (size_t)sA;
        BT += (size_t)z * (size_t)sB;
    }
    const int m0 = blockIdx.y*128, n0 = blockIdx.x*128;
    const int tid = threadIdx.x;
    const int w = tid>>6, l = tid&63;
    const int wm = (w>>1)*64, wn = (w&1)*64;
    const int lr = l&15, lk = (l>>4)*8, lq = l>>4;
    const int srow = tid>>2, kseg = tid&3;

    f4v acc[4][4];
    #pragma unroll
    for (int mi=0;mi<4;mi++)
      #pragma unroll
      for (int ni=0;ni<4;ni++)
        acc[mi][ni] = (f4v){0.0f,0.0f,0.0f,0.0f};

    for (int k0=kbeg;k0<kend;k0+=32){
        #pragma unroll
        for (int i=0;i<2;i++){
            int row = srow + i*64;
            int ga = m0+row;
            uint4 va = make_uint4(0u,0u,0u,0u);
            if (ga < M){
                if (ASEL == 2){
                    int isno = ga >> 12;
                    int r = ga & 4095; int b = r >> 10, n = r & 1023;
                    int kk = k0 + kseg*8;
                    if (kk < CSc){
                        const float* emb = isno ? (const float*)P2 : (const float*)A;
                        const int*   msk = isno ? DV2 : DV;
                        float m = (float)msk[((size_t)b*Tc + tpar)*Nc + n];
                        f4v e0 = *(const f4v*)(emb + (size_t)n*CSc + kk);
                        f4v e1 = *(const f4v*)(emb + (size_t)n*CSc + kk + 4);
                        f4v s0 = *(const f4v*)(PF + (size_t)n*(Bc*CSc) + b*CSc + kk);
                        f4v s1 = *(const f4v*)(PF + (size_t)n*(Bc*CSc) + b*CSc + kk + 4);
                        u16x8 tmp;
                        #pragma unroll
                        for (int j=0;j<4;j++) tmp[j]   = f2bf(m*(e0[j]+s0[j]));
                        #pragma unroll
                        for (int j=0;j<4;j++) tmp[4+j] = f2bf(m*(e1[j]+s1[j]));
                        va = *(uint4*)&tmp;
                    }
                } else if (ASEL == 3){
                    int ll = ga >> 7, be = ga & 127; int b = be >> 5, e = be & 31;
                    int kk = k0 + kseg*8;
                    if (kk < EDc){
                        int ev = DV[(((size_t)b*Tc + (Tc-1))*Ec + e)*Lc + ll];
                        const float* src = PF + (size_t)ev*EDc + kk;
                        f4v e0 = *(const f4v*)src;
                        f4v e1 = *(const f4v*)(src + 4);
                        u16x8 tmp;
                        #pragma unroll
                        for (int j=0;j<4;j++) tmp[j]   = f2bf(e0[j]);
                        #pragma unroll
                        for (int j=0;j<4;j++) tmp[4+j] = f2bf(e1[j]);
                        va = *(uint4*)&tmp;
                    }
                } else {
                    va = *(const uint4*)(A + (size_t)ga*lda + k0 + kseg*8);
                }
            }
            *(uint4*)&As[row*40 + kseg*8] = va;
            int gb = n0+row;
            uint4 vb = make_uint4(0u,0u,0u,0u);
            if (gb < N) vb = *(const uint4*)(BT + (size_t)gb*ldb + k0 + kseg*8);
            *(uint4*)&Bs[row*40 + kseg*8] = vb;
        }
        __syncthreads();
        s8v af[4], bfr[4];
        #pragma unroll
        for (int mi=0;mi<4;mi++) af[mi]  = *(const s8v*)&As[(wm+mi*16+lr)*40 + lk];
        #pragma unroll
        for (int ni=0;ni<4;ni++) bfr[ni] = *(const s8v*)&Bs[(wn+ni*16+lr)*40 + lk];
        #pragma unroll
        for (int mi=0;mi<4;mi++)
          #pragma unroll
          for (int ni=0;ni<4;ni++)
            acc[mi][ni] = __builtin_amdgcn_mfma_f32_16x16x32_bf16(af[mi], bfr[ni], acc[mi][ni], 0,0,0);
        __syncthreads();
    }

    #pragma unroll
    for (int mi=0;mi<4;mi++){
      #pragma unroll
      for (int ni=0;ni<4;ni++){
        int col = n0+wn+ni*16+lr;
        if (col >= N) continue;
        float bv_ = bias ? bias[col] : 0.0f;
        #pragma unroll
        for (int r=0;r<4;r++){
          int row = m0+wm+mi*16+lq*4+r;
          if (row >= M) continue;
          float x = acc[mi][ni][r] + bv_;
          if (EPIL == 0){
              float* C = (float*)P0;
              size_t base = (SPLITK>0) ? (size_t)z*(size_t)sC : 0;
              size_t grow = (SPLITK>0) ? (size_t)row : (size_t)z*M + row;
              C[base + grow*ldc + col] = x;
          } else if (EPIL == 1){
              x = (x>0.0f) ? x : 0.01f*x;
              if (row < 4096) ((ushort_t*)P0)[(size_t)row*KAB + col] = f2bf(x);
              else            ((ushort_t*)P1)[(size_t)(row-4096)*32 + col] = f2bf(x);
          } else if (EPIL == 5){
              if (col < 32)        ((ushort_t*)P0)[(size_t)row*32 + col] = f2bf(x);
              else if (col < 302)  ((ushort_t*)P1)[(size_t)(col-32)*4096 + row] = f2bf(x);
              else                 ((float*)P2)[(size_t)row*H4c + (col-302)] = x;
          }
        }
      }
    }
}

// ---------------------------------------------------------------------------
// Fused attention v2: P packed to bf16 MFMA layout in LDS during softmax.
// Grid (64, B), 256 threads, 1 block/CU.
// ---------------------------------------------------------------------------
__global__ __launch_bounds__(256)
void attn_fused_kernel(const ushort_t* __restrict__ no_prev, const ushort_t* __restrict__ u_embb,
                       const float* __restrict__ Wq, const float* __restrict__ bq,
                       const ushort_t* __restrict__ kb, const ushort_t* __restrict__ vT,
                       const int* __restrict__ divided, const float* __restrict__ hm1,
                       ushort_t* __restrict__ Abuf, float* __restrict__ hm23,
                       int t, int wr23)
{
    __shared__ float    scs[16*1028];    // 65792 B: scaled logits / exp values
    __shared__ ushort_t stg[288*72];     // 41472 B: K staging (ph1, stride 40) / V staging (ph3, stride 72)
    __shared__ ushort_t Pb[32*16*40];    // 40960 B: P bf16 [chunk][row][k] (qinS/WqS overlap in ph0)
    __shared__ ushort_t Qs[16*40];
    __shared__ float    mskS[1024];
    __shared__ float    hasS[4];
    float* qinS = (float*)Pb;            // [16][33]
    float* WqS  = (float*)&Pb[1056];     // [32][33]

    const int rt = blockIdx.x;
    const int b  = blockIdx.y;
    const int tid = threadIdx.x;
    const int w = tid>>6, l = tid&63, lr = l&15, lq = l>>4;
    const int lk8 = lq*8;
    const int row0 = rt*16;
    const size_t gq = (size_t)b*Nc + row0;

    // mask + has23
    bool lany = false;
    #pragma unroll
    for (int c4=0;c4<4;c4++){
        int c = tid*4 + c4;
        const int* dv = divided + (((size_t)b*Tc + t)*Nc + c)*3;
        bool m23 = (dv[1]>0)||(dv[2]>0);
        mskS[c] = m23 ? 1.0f : 0.0f;
        lany |= m23;
    }
    bool wany = __any(lany);
    if (l==0) hasS[w] = wany ? 1.0f : 0.0f;

    // zero V pad rows 270..287 of stg (stride-72 region, untouched by phase 1)
    for (int i=tid; i<18*72; i+=256) stg[270*72 + i] = 0;

    // qin staging (m3 select) + Wq
    for (int i=tid;i<16*32;i+=256){
        int r = i>>5, j = i&31;
        int n = row0 + r;
        bool m3 = divided[(((size_t)b*Tc+t)*Nc+n)*3+2] > 0;
        qinS[r*33+j] = m3 ? b2f(u_embb[(size_t)n*GSc+j]) : b2f(no_prev[(gq+r)*GSc+j]);
    }
    for (int i=tid;i<32*32;i+=256){
        int j=i>>5, o=i&31;
        WqS[j*33+o] = Wq[(size_t)j*ATc+o];
    }
    __syncthreads();
    const bool has = (hasS[0]+hasS[1]+hasS[2]+hasS[3]) > 0.5f;

    // q = qin @ Wq + bq -> Qs bf16
    {
        int r = tid>>4, o2 = (tid&15)*2;
        float a0 = bq[o2], a1 = bq[o2+1];
        for (int j=0;j<32;j++){
            float q = qinS[r*33+j];
            a0 += q*WqS[j*33+o2];
            a1 += q*WqS[j*33+o2+1];
        }
        Qs[r*40+o2]   = f2bf(a0);
        Qs[r*40+o2+1] = f2bf(a1);
    }
    __syncthreads();

    // phase 1: QK^T -> scs (pre-scaled)
    for (int kt=0;kt<8;kt++){
        #pragma unroll
        for (int i2=0;i2<2;i2++){
            int idx = tid*2+i2;
            int kr = idx>>2, seg = idx&3;
            *(uint4*)&stg[kr*40 + seg*8] =
                *(const uint4*)(kb + ((size_t)b*Nc + kt*128 + kr)*GSc + seg*8);
        }
        __syncthreads();
        s8v af = *(const s8v*)&Qs[lr*40 + lk8];
        #pragma unroll
        for (int ni=0;ni<2;ni++){
            int nt = w*2 + ni;
            s8v bf = *(const s8v*)&stg[(nt*16+lr)*40 + lk8];
            f4v a0 = (f4v){0,0,0,0};
            a0 = __builtin_amdgcn_mfma_f32_16x16x32_bf16(af, bf, a0, 0,0,0);
            #pragma unroll
            for (int r2=0;r2<4;r2++)
                scs[(lq*4+r2)*1028 + kt*128 + nt*16 + lr] = a0[r2]*INV_SQRT_AT_F;
        }
        __syncthreads();
    }

    // phase 2: masked softmax + pack normalized bf16 P into Pb.
    // Thread (r,i) owns row r, cols i+16j -- no cross-thread scs deps.
    {
        int r = tid>>4, i = tid&15;
        float m = -INFINITY;
        if (has){
            for (int j=0;j<64;j++){
                int c = i + 16*j;
                if (mskS[c] > 0.5f) m = fmaxf(m, scs[r*1028+c]);
            }
            #pragma unroll
            for (int o=1;o<16;o<<=1) m = fmaxf(m, __shfl_xor(m, o, 64));
        }
        float gm = has ? m : 0.0f;
        float s = 0.0f;
        for (int j=0;j<64;j++){
            int c = i + 16*j;
            float p;
            if (has) p = (mskS[c]>0.5f) ? expf(scs[r*1028+c]-gm) : 0.0f;
            else     p = 1.0f;
            scs[r*1028+c] = p;
            s += p;
        }
        #pragma unroll
        for (int o=1;o<16;o<<=1) s += __shfl_xor(s, o, 64);
        float inv = 1.0f/s;
        #pragma unroll 4
        for (int j2=0;j2<32;j2++){
            int c = 2*i + 32*j2;                 // chunk=j2, k=2i
            float p0 = scs[r*1028+c]*inv;
            float p1 = scs[r*1028+c+1]*inv;
            unsigned int pk = (unsigned int)f2bf(p0) | ((unsigned int)f2bf(p1)<<16);
            *(unsigned int*)&Pb[(size_t)j2*640 + r*40 + 2*i] = pk;
        }
    }
    __syncthreads();

    // phase 3: PV -- A from Pb (b128, no cvt), B = V^T staged per 64-col chunk
    f4v acc[5];
    #pragma unroll
    for (int j5=0;j5<5;j5++) acc[j5] = (f4v){0,0,0,0};
    for (int vc=0;vc<16;vc++){
        for (int idx=tid; idx<2160; idx+=256){
            int n = idx>>3, seg = idx&7;
            *(uint4*)&stg[n*72 + seg*8] =
                *(const uint4*)(vT + (size_t)n*(Bc*Nc) + (size_t)b*Nc + vc*64 + seg*8);
        }
        __syncthreads();
        #pragma unroll
        for (int ki=0;ki<2;ki++){
            int chunk = vc*2 + ki;
            s8v af = *(const s8v*)&Pb[(size_t)chunk*640 + lr*40 + lk8];
            #pragma unroll
            for (int j5=0;j5<5;j5++){
                int nt = w + 4*j5;
                if (nt < 18){
                    s8v bf = *(const s8v*)&stg[(nt*16+lr)*72 + ki*32 + lk8];
                    acc[j5] = __builtin_amdgcn_mfma_f32_16x16x32_bf16(af, bf, acc[j5], 0,0,0);
                }
            }
        }
        __syncthreads();
    }

    // phase 4: tanh + h-update epilogue
    #pragma unroll
    for (int j5=0;j5<5;j5++){
        int nt = w + 4*j5;
        if (nt >= 18) continue;
        int col = nt*16 + lr;
        if (col >= Hc) continue;
        #pragma unroll
        for (int r2=0;r2<4;r2++){
            int row16 = lq*4 + r2;
            size_t grow = gq + row16;
            int n = row0 + row16;
            const int* dv = divided + (((size_t)b*Tc + t)*Nc + n)*3;
            bool m1  = dv[0]>0;
            bool m23 = (dv[1]>0)||(dv[2]>0);
            float xt = tanhf(acc[j5][r2]);
            float hv = m23 ? xt : (m1 ? hm1[grow*Hc + col] : 0.0f);
            Abuf[grow*KAB + 32 + col] = f2bf(hv);
            if (wr23) hm23[grow*Hc + col] = xt;
        }
    }
}

// ---------------------------------------------------------------------------
// f32 tiled GEMM (final layer). ACT 3 = sigmoid.
// ---------------------------------------------------------------------------
template<int ACT>
__global__ __launch_bounds__(256)
void gemm_kernel(const float* __restrict__ A, const float* __restrict__ Bm,
                 const float* __restrict__ bias, float* __restrict__ C,
                 int M, int Nn, int K)
{
    constexpr int BM=64, BN=64, BK=16;
    __shared__ float As[BK][BM+4];
    __shared__ float Bs[BK][BN+4];
    const int row0 = blockIdx.y*BM, col0 = blockIdx.x*BN;
    const int tid = threadIdx.x;
    const int tr = (tid>>4)<<2;
    const int tc = (tid&15)<<2;
    const int ar = tid>>2;
    const int ac = (tid&3)<<2;
    const int br = tid>>4;
    const int bc = (tid&15)<<2;
    float acc[4][4] = {};
    for (int k0=0;k0<K;k0+=BK){
        #pragma unroll
        for (int i=0;i<4;i++){
            int gr=row0+ar, gc=k0+ac+i;
            As[ac+i][ar] = (gr<M && gc<K) ? A[(size_t)gr*K+gc] : 0.0f;
        }
        #pragma unroll
        for (int i=0;i<4;i++){
            int gr=k0+br, gc=col0+bc+i;
            Bs[br][bc+i] = (gr<K && gc<Nn) ? Bm[(size_t)gr*Nn+gc] : 0.0f;
        }
        __syncthreads();
        #pragma unroll
        for (int kk=0;kk<BK;kk++){
            float a0=As[kk][tr+0], a1=As[kk][tr+1], a2=As[kk][tr+2], a3=As[kk][tr+3];
            float b0=Bs[kk][tc+0], b1=Bs[kk][tc+1], b2=Bs[kk][tc+2], b3=Bs[kk][tc+3];
            acc[0][0]+=a0*b0; acc[0][1]+=a0*b1; acc[0][2]+=a0*b2; acc[0][3]+=a0*b3;
            acc[1][0]+=a1*b0; acc[1][1]+=a1*b1; acc[1][2]+=a1*b2; acc[1][3]+=a1*b3;
            acc[2][0]+=a2*b0; acc[2][1]+=a2*b1; acc[2][2]+=a2*b2; acc[2][3]+=a2*b3;
            acc[3][0]+=a3*b0; acc[3][1]+=a3*b1; acc[3][2]+=a3*b2; acc[3][3]+=a3*b3;
        }
        __syncthreads();
    }
    #pragma unroll
    for (int i=0;i<4;i++){
        int r=row0+tr+i; if (r>=M) continue;
        #pragma unroll
        for (int j=0;j<4;j++){
            int c=col0+tc+j; if (c>=Nn) continue;
            float x = acc[i][j];
            if (bias) x += bias[c];
            if (ACT==3) x = 1.0f/(1.0f+expf(-x));
            C[(size_t)r*Nn+c] = x;
        }
    }
}

// ---------------------------------------------------------------------------
// Prep: all weight conversions + zero-fills (cascading ranges).
// ---------------------------------------------------------------------------
#define PR0 32768LL     // u_embb
#define PR1 2048LL      // WgT [32][64]
#define PR3 442240LL    // WB [1382][320]
#define PR4 1382LL      // biasB
#define PR5 449280LL    // WTl [1080][416]
#define PR6 313344LL    // WhhRT [17][64][288]
#define PR7 73728LL     // zero hbLA+hbLB
#define PR8 8LL         // zero bar
#define PR9 1310720LL   // zero Abuf [4096][320]
#define PRTOT (PR0+PR1+PR3+PR4+PR5+PR6+PR7+PR8+PR9)

__global__ void prep_kernel(const float* __restrict__ u_emb,
                            const float* __restrict__ Wg,
                            const float* __restrict__ Wk, const float* __restrict__ Wv,
                            const float* __restrict__ gru_Wih, const float* __restrict__ gru_Whh,
                            const float* __restrict__ bk, const float* __restrict__ bv,
                            const float* __restrict__ gru_bih, const float* __restrict__ gru_bhh,
                            const float* __restrict__ lstm_Wih, const float* __restrict__ lstm_Whh,
                            ushort_t* u_embb, ushort_t* WgT,
                            ushort_t* WB, float* biasB, ushort_t* WTl, ushort_t* WhhRT,
                            ushort_t* hbLA, ushort_t* hbLB, unsigned int* bar, ushort_t* Abuf)
{
    long long idx = (long long)blockIdx.x*256 + threadIdx.x;
    if (idx < PR0){ u_embb[idx] = f2bf(u_emb[idx]); return; } idx -= PR0;
    if (idx < PR1){ int n=(int)(idx>>6), k=(int)(idx&63);
        WgT[idx] = (k<CSc) ? f2bf(Wg[(size_t)k*GSc+n]) : (ushort_t)0; return; } idx -= PR1;
    if (idx < PR3){
        int n=(int)(idx/KAB), k=(int)(idx%KAB);
        float v = 0.0f;
        if (n < 32){            if (k<32) v = Wk[(size_t)k*ATc + n]; }
        else if (n < 302){      if (k<32) v = Wv[(size_t)k*Hc + (n-32)]; }
        else if (n < 572){ int j=n-302;
            if (k<32) v = gru_Wih[(size_t)k*H3c + j];
            else if (k<302) v = gru_Whh[(size_t)(k-32)*H3c + j]; }
        else if (n < 842){ int j=(n-572)+270;
            if (k<32) v = gru_Wih[(size_t)k*H3c + j];
            else if (k<302) v = gru_Whh[(size_t)(k-32)*H3c + j]; }
        else if (n < 1112){ int j=(n-842)+540;
            if (k<32) v = gru_Wih[(size_t)k*H3c + j]; }
        else { int j=(n-1112)+540;
            if (k>=32 && k<302) v = gru_Whh[(size_t)(k-32)*H3c + j]; }
        WB[idx] = f2bf(v); return; } idx -= PR3;
    if (idx < PR4){
        int n = (int)idx; float v;
        if (n < 32)        v = bk[n];
        else if (n < 302)  v = bv[n-32];
        else if (n < 572)  v = gru_bih[n-302] + gru_bhh[n-302];
        else if (n < 842)  v = gru_bih[(n-572)+270] + gru_bhh[(n-572)+270];
        else if (n < 1112) v = gru_bih[(n-842)+540];
        else               v = gru_bhh[(n-1112)+540];
        biasB[n] = v; return; } idx -= PR4;
    if (idx < PR5){ int n=(int)(idx/KPE), k=(int)(idx%KPE);
        WTl[idx] = (k<EDc) ? f2bf(lstm_Wih[(size_t)k*H4c+n]) : (ushort_t)0; return; } idx -= PR5;
    if (idx < PR6){
        int jg=(int)(idx/(64*288)); int r2=(int)(idx%(64*288));
        int n=r2/288, k=r2%288;
        int gate=n>>4, jj=n&15, j=jg*16+jj;
        WhhRT[idx] = (k<Hc && j<Hc) ? f2bf(lstm_Whh[(size_t)k*H4c + gate*Hc + j]) : (ushort_t)0;
        return; } idx -= PR6;
    if (idx < PR7){ if (idx < 36864) hbLA[idx] = 0; else hbLB[idx-36864] = 0; return; } idx -= PR7;
    if (idx < PR8){ bar[idx] = 0u; return; } idx -= PR8;
    if (idx < PR9){ Abuf[idx] = 0; }
}

// ---------------------------------------------------------------------------
// adj nonzero-list build (adj entries are exactly 0.0/1.0)
// ---------------------------------------------------------------------------
__global__ void nz_build_kernel(const float* __restrict__ adj, int* __restrict__ nzc,
                                int* __restrict__ nzidx)
{
    int n = blockIdx.x;
    __shared__ int cnt;
    if (threadIdx.x == 0) cnt = 0;
    __syncthreads();
    for (int k = threadIdx.x; k < Nc; k += 256){
        if (adj[(size_t)n*Nc + k] != 0.0f){
            int pos = atomicAdd(&cnt, 1);
            if (pos < NZCAP) nzidx[(size_t)n*NZCAP + pos] = k;
        }
    }
    __syncthreads();
    if (threadIdx.x == 0) nzc[n] = (cnt < NZCAP) ? cnt : NZCAP;
}

// ---------------------------------------------------------------------------
// Sparse S: S[n][b*CS+c] = sum_{k in nz(n)} cm(b,k)*c_emb[k][c] + nm(b,k)*n_emb[k][c]
// ---------------------------------------------------------------------------
__global__ __launch_bounds__(192)
void s_sparse_kernel(const int* __restrict__ code_x, const int* __restrict__ neighbors,
                     const float* __restrict__ c_emb, const float* __restrict__ n_emb,
                     const int* __restrict__ nzc, const int* __restrict__ nzidx,
                     int t, float* __restrict__ S)
{
    int n = blockIdx.x;
    int tid = threadIdx.x;
    int b = tid / CSc, c = tid % CSc;
    int cnt = nzc[n];
    float s = 0.0f;
    for (int i=0; i<cnt; i++){
        int k = nzidx[(size_t)n*NZCAP + i];
        int cm = code_x  [((size_t)b*Tc+t)*Nc + k];
        int nm = neighbors[((size_t)b*Tc+t)*Nc + k];
        float e = 0.0f;
        if (cm) e += c_emb[(size_t)k*CSc + c];
        if (nm) e += n_emb[(size_t)k*CSc + c];
        s += e;
    }
    S[(size_t)n*(Bc*CSc) + tid] = s;
}

// ---------------------------------------------------------------------------
// GRU combine (t>=1): gsum layout [r][1080] = r|z|in|hn
// ---------------------------------------------------------------------------
__global__ void gru_combine_kernel(const float* __restrict__ gsum, const ushort_t* __restrict__ Abuf,
                                   float* __restrict__ hm1)
{
    int r = blockIdx.x;
    const float* G = gsum + (size_t)r*H4c;
    for (int j = threadIdx.x; j < Hc; j += blockDim.x){
        float rg = sigmoid_f(G[j]);
        float zg = sigmoid_f(G[270+j]);
        float ng = tanhf(G[540+j] + rg*G[810+j]);
        float h  = b2f(Abuf[(size_t)r*KAB + 32 + j]);
        hm1[(size_t)r*Hc + j] = (1.0f-zg)*ng + zg*h;
    }
}

// t=0: h=0; write h_new = m1 ? (1-z)*n : 0 directly into Abuf
__global__ void gru_combine_t0_kernel(const float* __restrict__ gsum, const int* __restrict__ divided,
                                      ushort_t* __restrict__ Abuf)
{
    int r = blockIdx.x;
    int b = r >> 10, n = r & 1023;
    bool m1 = divided[(((size_t)b*Tc+0)*Nc+n)*3 + 0] > 0;
    const float* G = gsum + (size_t)r*H4c;
    for (int j = threadIdx.x; j < Hc; j += blockDim.x){
        float rg = sigmoid_f(G[j]);
        float zg = sigmoid_f(G[270+j]);
        float ng = tanhf(G[540+j] + rg*G[810+j]);
        float hv = (1.0f-zg)*ng;
        Abuf[(size_t)r*KAB + 32 + j] = m1 ? f2bf(hv) : (ushort_t)0;
    }
}

// ---------------------------------------------------------------------------
// out_last reduction (t=5), coalesced
// ---------------------------------------------------------------------------
__global__ __launch_bounds__(320)
void outlast_partial_kernel(const int* __restrict__ divided,
                            const float* __restrict__ hm1, const float* __restrict__ hm23,
                            float* __restrict__ part1, float* __restrict__ part23)
{
    int nc = blockIdx.x, b = blockIdx.y;
    int j = threadIdx.x;
    if (j >= Hc) return;
    float m1v = -INFINITY, m23v = -INFINITY;
    #pragma unroll 4
    for (int n = nc*32; n < nc*32+32; n++){
        const int* dv = divided + (((size_t)b*Tc + (Tc-1))*Nc + n)*3;
        bool m1  = dv[0] > 0;
        bool m23 = (dv[1] > 0) || (dv[2] > 0);
        size_t o = ((size_t)b*Nc+n)*Hc + j;
        if (m1)  m1v  = fmaxf(m1v,  hm1[o]);
        if (m23) m23v = fmaxf(m23v, hm23[o]);
    }
    part1 [((size_t)b*32+nc)*320 + j] = m1v;
    part23[((size_t)b*32+nc)*320 + j] = m23v;
}

__global__ __launch_bounds__(320)
void outlast_combine_kernel(const float* __restrict__ part1, const float* __restrict__ part23,
                            float* __restrict__ outlast)
{
    int b = blockIdx.x; int j = threadIdx.x;
    if (j >= Hc) return;
    float a = -INFINITY, c = -INFINITY;
    for (int nc=0;nc<32;nc++){
        a = fmaxf(a, part1 [((size_t)b*32+nc)*320 + j]);
        c = fmaxf(c, part23[((size_t)b*32+nc)*320 + j]);
    }
    outlast[(size_t)b*Hc + j] = (a==-INFINITY ? 0.0f : a) + (c==-INFINITY ? 0.0f : c);
}

// ---------------------------------------------------------------------------
// Persistent LSTM: 68 blocks (4 cellgroups x 17 jgroups), all 32 steps with
// agent-scope global barrier. Whh fragments preloaded in registers (invariant),
// c-state in registers (block-exclusive), h ping-pongs in global bf16.
// ---------------------------------------------------------------------------
__global__ __launch_bounds__(256)
void lstm_persist(const float* __restrict__ gx_all,     // [32][128][1080]
                  const ushort_t* __restrict__ WhhRT,   // [17][64][288]
                  ushort_t* __restrict__ hbA, ushort_t* __restrict__ hbB,
                  unsigned int* __restrict__ bar,
                  float* __restrict__ hev_out)          // [128][270]
{
    int cg = blockIdx.x & 3, jg = blockIdx.x >> 2;
    int tid = threadIdx.x;
    int w = tid>>6, l = tid&63;
    int mi = w>>1, ni0 = (w&1)*2;
    int arow = cg*32 + mi*16 + (l&15);
    int koff = (l>>4)*8;
    const ushort_t* Wb = WhhRT + (size_t)jg*64*288;

    // preload invariant W fragments (72 VGPRs)
    s8v bf0[9], bf1[9];
    #pragma unroll
    for (int kc=0;kc<9;kc++){
        bf0[kc] = *(const s8v*)(Wb + (size_t)(ni0*16 + (l&15))*288 + kc*32 + koff);
        bf1[kc] = *(const s8v*)(Wb + (size_t)((ni0+1)*16 + (l&15))*288 + kc*32 + koff);
    }

    __shared__ float gs[32][64];
    int cl0 = tid>>4, jj0 = tid&15;
    int j = jg*16 + jj0;
    bool jok = (j < Hc);
    float c0 = 0.0f, c1 = 0.0f;
    int crow = mi*16 + (l>>4)*4, ccol = l&15;

    for (int st=0; st<Lc; st++){
        const ushort_t* hin  = (st&1) ? hbB : hbA;
        ushort_t*       hout = (st&1) ? hbA : hbB;
        const float* gx = gx_all + (size_t)st*BEc*H4c;

        f4v acc0=(f4v){0,0,0,0}, acc1=(f4v){0,0,0,0};
        #pragma unroll
        for (int kc=0;kc<9;kc++){
            s8v a = *(const s8v*)(hin + (size_t)arow*288 + kc*32 + koff);
            acc0 = __builtin_amdgcn_mfma_f32_16x16x32_bf16(a, bf0[kc], acc0, 0,0,0);
            acc1 = __builtin_amdgcn_mfma_f32_16x16x32_bf16(a, bf1[kc], acc1, 0,0,0);
        }
        #pragma unroll
        for (int r=0;r<4;r++){
            gs[crow+r][ni0*16 + ccol]     = acc0[r];
            gs[crow+r][(ni0+1)*16 + ccol] = acc1[r];
        }
        __syncthreads();
        if (jok){
            {
                int cell = cg*32 + cl0;
                const float* g = gx + (size_t)cell*H4c;
                float ig = sigmoid_f(gs[cl0][jj0]    + g[j]);
                float fg = sigmoid_f(gs[cl0][16+jj0] + g[Hc+j]);
                float gg = tanhf    (gs[cl0][32+jj0] + g[2*Hc+j]);
                float og = sigmoid_f(gs[cl0][48+jj0] + g[3*Hc+j]);
                float cn = fg*c0 + ig*gg; c0 = cn;
                float hn = og*tanhf(cn);
                hout[(size_t)cell*288 + j] = f2bf(hn);
                if (st == Lc-1) hev_out[(size_t)cell*Hc + j] = hn;
            }
            {
                int cell = cg*32 + 16 + cl0;
                const float* g = gx + (size_t)cell*H4c;
                float ig = sigmoid_f(gs[16+cl0][jj0]    + g[j]);
                float fg = sigmoid_f(gs[16+cl0][16+jj0] + g[Hc+j]);
                float gg = tanhf    (gs[16+cl0][32+jj0] + g[2*Hc+j]);
                float og = sigmoid_f(gs[16+cl0][48+jj0] + g[3*Hc+j]);
                float cn = fg*c1 + ig*gg; c1 = cn;
                float hn = og*tanhf(cn);
                hout[(size_t)cell*288 + j] = f2bf(hn);
                if (st == Lc-1) hev_out[(size_t)cell*Hc + j] = hn;
            }
        }
        __syncthreads();
        if (st < Lc-1){
            if (tid == 0){
                __hip_atomic_fetch_add(bar, 1u, __ATOMIC_ACQ_REL, __HIP_MEMORY_SCOPE_AGENT);
                unsigned int tgt = 68u*(unsigned)(st+1);
                while (__hip_atomic_load(bar, __ATOMIC_ACQUIRE, __HIP_MEMORY_SCOPE_AGENT) < tgt)
                    __builtin_amdgcn_s_sleep(2);
            }
            __syncthreads();
        }
    }
}

// ---------------------------------------------------------------------------
// heads: wdc + dp_attention over [outlast ; hev] -> o1 (o2 == o1)
// ---------------------------------------------------------------------------
__global__ __launch_bounds__(256)
void heads_kernel(const float* __restrict__ outlast, const float* __restrict__ hev,
                  const float* __restrict__ Wd, const float* __restrict__ bd,
                  const float* __restrict__ ctx, float* __restrict__ o1)
{
    int b = blockIdx.x, tid = threadIdx.x;
    __shared__ float wdc[Hc+1];
    __shared__ float sc[Ec+1];
    for (int j=tid;j<Hc;j+=256){
        float s = 0.0f;
        for (int d=0;d<DAc;d++) s += Wd[(size_t)j*DAc+d]*ctx[d];
        wdc[j] = s;
    }
    if (tid == 255){
        float s = 0.0f;
        for (int d=0;d<DAc;d++) s += bd[d]*ctx[d];
        wdc[Hc] = s;
    }
    __syncthreads();
    if (tid < Ec+1){
        const float* x = (tid==0) ? (outlast + (size_t)b*Hc)
                                  : (hev + ((size_t)b*Ec + tid-1)*Hc);
        float s = wdc[Hc];
        for (int j=0;j<Hc;j++) s += x[j]*wdc[j];
        sc[tid] = s;
    }
    __syncthreads();
    if (tid == 0){
        float m = -INFINITY;
        for (int s=0;s<Ec+1;s++) m = fmaxf(m, sc[s]);
        float sum = 0.0f;
        for (int s=0;s<Ec+1;s++){ sc[s] = expf(sc[s]-m); sum += sc[s]; }
        float inv = 1.0f/sum;
        for (int s=0;s<Ec+1;s++) sc[s] *= inv;
    }
    __syncthreads();
    for (int j=tid;j<Hc;j+=256){
        float acc = sc[0]*outlast[(size_t)b*Hc + j];
        for (int e=0;e<Ec;e++) acc += sc[1+e]*hev[((size_t)b*Ec+e)*Hc + j];
        o1[(size_t)b*Hc + j] = acc;
    }
}

// ---------------------------------------------------------------------------
extern "C" void kernel_launch(void* const* d_in, const int* in_sizes, int n_in,
                              void* d_out, int out_size, void* d_ws, size_t ws_size,
                              hipStream_t stream)
{
    const int*   code_x    = (const int*)d_in[0];
    const int*   divided   = (const int*)d_in[1];
    const int*   neighbors = (const int*)d_in[2];
    const int*   events    = (const int*)d_in[4];
    const float* c_emb     = (const float*)d_in[5];
    const float* n_emb     = (const float*)d_in[6];
    const float* u_emb     = (const float*)d_in[7];
    const float* adj       = (const float*)d_in[8];
    const float* Wg        = (const float*)d_in[9];
    const float* bg        = (const float*)d_in[10];
    const float* gru_Wih   = (const float*)d_in[11];
    const float* gru_Whh   = (const float*)d_in[12];
    const float* gru_bih   = (const float*)d_in[13];
    const float* gru_bhh   = (const float*)d_in[14];
    const float* Wq        = (const float*)d_in[15];
    const float* bq        = (const float*)d_in[16];
    const float* Wk        = (const float*)d_in[17];
    const float* bk        = (const float*)d_in[18];
    const float* Wv        = (const float*)d_in[19];
    const float* bv        = (const float*)d_in[20];
    const float* Wd        = (const float*)d_in[21];
    const float* bd        = (const float*)d_in[22];
    const float* ctx       = (const float*)d_in[23];
    const float* Eemb      = (const float*)d_in[24];
    const float* lstm_Wih  = (const float*)d_in[25];
    const float* lstm_Whh  = (const float*)d_in[26];
    const float* lstm_b    = (const float*)d_in[27];
    const float* Wc        = (const float*)d_in[28];
    const float* bc        = (const float*)d_in[29];
    float* out = (float*)d_out;

    float* ws = (float*)d_ws;
    size_t off = 0;
    auto alloc = [&](size_t n){ n = (n+7)&~(size_t)7; float* p = ws + off; off += n; return p; };
    auto allocU = [&](size_t n){ return (ushort_t*)alloc((n+1)/2); };

    float* hm1     = alloc((size_t)Bc*Nc*Hc);
    float* hm23    = alloc((size_t)Bc*Nc*Hc);
    float* S       = alloc((size_t)Nc*Bc*CSc);
    float* gsum    = alloc((size_t)Bc*Nc*H4c);          // also gatesx (lstm) alias
    ushort_t* Abuf  = allocU((size_t)Bc*Nc*KAB);        // [4096][320]: co | h | pad
    ushort_t* noA   = allocU((size_t)Bc*Nc*GSc);
    ushort_t* noB   = allocU((size_t)Bc*Nc*GSc);
    ushort_t* kb    = allocU((size_t)Bc*Nc*ATc);
    ushort_t* vT    = allocU((size_t)Hc*Bc*Nc);
    ushort_t* u_embb= allocU((size_t)Nc*GSc);
    ushort_t* WgT   = allocU((size_t)GSc*KPG);
    ushort_t* WB    = allocU((size_t)NCMB*KAB);
    ushort_t* WTl   = allocU((size_t)H4c*KPE);
    ushort_t* WhhRT = allocU((size_t)17*64*288);
    ushort_t* hbLA  = allocU((size_t)BEc*288);
    ushort_t* hbLB  = allocU((size_t)BEc*288);
    unsigned int* bar = (unsigned int*)alloc(8);
    float* biasB   = alloc((size_t)NCMB);
    int*   nzc     = (int*)alloc((size_t)Nc);
    int*   nzidx   = (int*)alloc((size_t)Nc*NZCAP);
    float* outlast = alloc((size_t)Bc*Hc);
    float* o1      = alloc((size_t)Bc*Hc);
    float* hev     = alloc((size_t)BEc*Hc);
    float* part1   = alloc((size_t)Bc*32*320);
    float* part23  = alloc((size_t)Bc*32*320);

    float* gatesx  = gsum;     // lstm input gates alias (post-loop)
    (void)ws_size; (void)in_sizes; (void)n_in; (void)out_size;

    // ---- prep: conversions + zero fills; adj nz-lists ----
    {
        long long nb = (PRTOT + 255) / 256;
        prep_kernel<<<dim3((unsigned)nb), dim3(256), 0, stream>>>(
            u_emb, Wg, Wk, Wv, gru_Wih, gru_Whh, bk, bv, gru_bih, gru_bhh,
            lstm_Wih, lstm_Whh,
            u_embb, WgT, WB, biasB, WTl, WhhRT, hbLA, hbLB, bar, Abuf);
        nz_build_kernel<<<dim3(Nc), dim3(256), 0, stream>>>(adj, nzc, nzidx);
    }

    ushort_t* no_prev = noB;
    ushort_t* no_cur  = noA;
    for (int t=0; t<Tc; t++){
        s_sparse_kernel<<<dim3(Nc), dim3(192), 0, stream>>>(code_x, neighbors, c_emb, n_emb,
                                                            nzc, nzidx, t, S);
        // co|no = leaky((mask*(emb+S)) @ Wg + bg): A built on the fly (ASEL2)
        mfma_k<1,0,2><<<dim3(1,64,1),256,0,stream>>>(
            (const ushort_t*)c_emb, WgT, bg,
            Abuf, no_cur, (void*)n_emb, S, code_x, neighbors,
            2*Bc*Nc, GSc, KPG, 0, KPG, 0, 0,0,0, t);
        // combined k|v|gates = [co|h] @ WB + biasB
        mfma_k<5,0,0><<<dim3(11,32,1),256,0,stream>>>(
            Abuf, WB, biasB,
            kb, vT, gsum, nullptr, nullptr, nullptr,
            Bc*Nc, NCMB, KAB, KAB, KAB, 0, 0,0,0, 0);
        if (t == 0){
            gru_combine_t0_kernel<<<dim3(Bc*Nc), dim3(256), 0, stream>>>(gsum, divided, Abuf);
        } else {
            gru_combine_kernel<<<dim3(Bc*Nc), dim3(256), 0, stream>>>(gsum, Abuf, hm1);
            // fused attention: qin-select + q + QK^T + softmax + PV + h-update
            attn_fused_kernel<<<dim3(64, Bc), dim3(256), 0, stream>>>(
                no_prev, u_embb, Wq, bq, kb, vT, divided, hm1,
                Abuf, hm23, t, (t == Tc-1) ? 1 : 0);
            if (t == Tc-1){
                outlast_partial_kernel<<<dim3(32, Bc), dim3(320), 0, stream>>>(divided, hm1, hm23, part1, part23);
                outlast_combine_kernel<<<dim3(Bc), dim3(320), 0, stream>>>(part1, part23, outlast);
            }
        }
        ushort_t* tmp = no_prev; no_prev = no_cur; no_cur = tmp;
    }

    // ---- LSTM over last-visit events ----
    mfma_k<0,0,3><<<dim3(9,32,1),256,0,stream>>>(
        nullptr, WTl, lstm_b,
        gatesx, nullptr, nullptr, Eemb, events, nullptr,
        BEc*Lc, H4c, KPE, 0, KPE, H4c, 0,0,0, 0);
    lstm_persist<<<dim3(68), dim3(256), 0, stream>>>(gatesx, WhhRT, hbLA, hbLB, bar, hev);

    // ---- heads ----
    heads_kernel<<<dim3(Bc), dim3(256), 0, stream>>>(outlast, hev, Wd, bd, ctx, o1);
    {
        dim3 grid((OUTc+63)/64, 1, 1);
        gemm_kernel<3><<<grid,dim3(256),0,stream>>>(o1, Wc, bc, out, Bc, OUTc, Hc);
    }
}

// Round 9
// 1054.718 us; speedup vs baseline: 1.2272x; 1.2272x over previous
//
#include <hip/hip_runtime.h>
#include <hip/hip_bf16.h>
#include <math.h>

// Problem constants
#define Bc   4
#define Tc   6
#define Nc   1024
#define CSc  48
#define GSc  32
#define Hc   270
#define ATc  32
#define DAc  64
#define Ec   32
#define Lc   32
#define EDc  400
#define OUTc 4000
#define H3c  810
#define H4c  1080
#define BEc  128
#define KPE  416    // ED padded
#define KPG  64     // CS padded
#define KAB  320    // Abuf K: 32 co + 270 h + 18 pad
#define NCMB 1382   // combined N: 32 k + 270 v + 270 r + 270 z + 270 in + 270 hn
#define NZCAP 96
#define INV_SQRT_AT_F 0.17677669529663687f

typedef unsigned short ushort_t;
using s8v  = __attribute__((ext_vector_type(8))) short;
using f4v  = __attribute__((ext_vector_type(4))) float;
using u16x8= __attribute__((ext_vector_type(8))) unsigned short;

__device__ __forceinline__ float sigmoid_f(float x){ return 1.0f/(1.0f+expf(-x)); }
__device__ __forceinline__ ushort_t f2bf(float x){
    __hip_bfloat16 b = __float2bfloat16(x);
    return *reinterpret_cast<ushort_t*>(&b);
}
__device__ __forceinline__ float b2f(ushort_t u){
    return __uint_as_float(((unsigned int)u)<<16);
}

// ---------------------------------------------------------------------------
// bf16 MFMA GEMM, 128x128 tile, 4 waves.
// EPIL 0: f32 store (+bias)
// EPIL 1: leaky-relu dual bf16: row<4096 -> Abuf (stride KAB), else no (stride 32)
// EPIL 5: combined: col<32 -> kSw (swizzled frag layout); col<302 -> vSw
//         (swizzled frag layout); else gsum f32
// ASEL 2: cono on-the-fly: A=c_emb(f32), P2=n_emb(f32), PF=S, DV=code_x, DV2=neighbors
// ASEL 3: lstm gather: PF=Eemb(f32), DV=events
// ---------------------------------------------------------------------------
template<int EPIL, int SPLITK, int ASEL>
__global__ __launch_bounds__(256)
void mfma_k(const ushort_t* __restrict__ A, const ushort_t* __restrict__ BT,
            const float* __restrict__ bias,
            void* __restrict__ P0, void* __restrict__ P1, void* __restrict__ P2,
            const float* __restrict__ PF, const int* __restrict__ DV,
            const int* __restrict__ DV2,
            int M, int N, int Kp, int lda, int ldb, int ldc,
            long long sA, long long sB, long long sC, int tpar)
{
    __shared__ ushort_t As[128*40];
    __shared__ ushort_t Bs[128*40];
    const int z = blockIdx.z;
    int kbeg = 0, kend = Kp;
    if (SPLITK > 0){
        int ks = Kp / SPLITK;
        kbeg = z*ks; kend = kbeg + ks;
    } else {
        if (ASEL == 0) A += (size_t)z * (size_t)sA;
        BT += (size_t)z * (size_t)sB;
    }
    const int m0 = blockIdx.y*128, n0 = blockIdx.x*128;
    const int tid = threadIdx.x;
    const int w = tid>>6, l = tid&63;
    const int wm = (w>>1)*64, wn = (w&1)*64;
    const int lr = l&15, lk = (l>>4)*8, lq = l>>4;
    const int srow = tid>>2, kseg = tid&3;

    f4v acc[4][4];
    #pragma unroll
    for (int mi=0;mi<4;mi++)
      #pragma unroll
      for (int ni=0;ni<4;ni++)
        acc[mi][ni] = (f4v){0.0f,0.0f,0.0f,0.0f};

    for (int k0=kbeg;k0<kend;k0+=32){
        #pragma unroll
        for (int i=0;i<2;i++){
            int row = srow + i*64;
            int ga = m0+row;
            uint4 va = make_uint4(0u,0u,0u,0u);
            if (ga < M){
                if (ASEL == 2){
                    int isno = ga >> 12;
                    int r = ga & 4095; int b = r >> 10, n = r & 1023;
                    int kk = k0 + kseg*8;
                    if (kk < CSc){
                        const float* emb = isno ? (const float*)P2 : (const float*)A;
                        const int*   msk = isno ? DV2 : DV;
                        float m = (float)msk[((size_t)b*Tc + tpar)*Nc + n];
                        f4v e0 = *(const f4v*)(emb + (size_t)n*CSc + kk);
                        f4v e1 = *(const f4v*)(emb + (size_t)n*CSc + kk + 4);
                        f4v s0 = *(const f4v*)(PF + (size_t)n*(Bc*CSc) + b*CSc + kk);
                        f4v s1 = *(const f4v*)(PF + (size_t)n*(Bc*CSc) + b*CSc + kk + 4);
                        u16x8 tmp;
                        #pragma unroll
                        for (int j=0;j<4;j++) tmp[j]   = f2bf(m*(e0[j]+s0[j]));
                        #pragma unroll
                        for (int j=0;j<4;j++) tmp[4+j] = f2bf(m*(e1[j]+s1[j]));
                        va = *(uint4*)&tmp;
                    }
                } else if (ASEL == 3){
                    int ll = ga >> 7, be = ga & 127; int b = be >> 5, e = be & 31;
                    int kk = k0 + kseg*8;
                    if (kk < EDc){
                        int ev = DV[(((size_t)b*Tc + (Tc-1))*Ec + e)*Lc + ll];
                        const float* src = PF + (size_t)ev*EDc + kk;
                        f4v e0 = *(const f4v*)src;
                        f4v e1 = *(const f4v*)(src + 4);
                        u16x8 tmp;
                        #pragma unroll
                        for (int j=0;j<4;j++) tmp[j]   = f2bf(e0[j]);
                        #pragma unroll
                        for (int j=0;j<4;j++) tmp[4+j] = f2bf(e1[j]);
                        va = *(uint4*)&tmp;
                    }
                } else {
                    va = *(const uint4*)(A + (size_t)ga*lda + k0 + kseg*8);
                }
            }
            *(uint4*)&As[row*40 + kseg*8] = va;
            int gb = n0+row;
            uint4 vb = make_uint4(0u,0u,0u,0u);
            if (gb < N) vb = *(const uint4*)(BT + (size_t)gb*ldb + k0 + kseg*8);
            *(uint4*)&Bs[row*40 + kseg*8] = vb;
        }
        __syncthreads();
        s8v af[4], bfr[4];
        #pragma unroll
        for (int mi=0;mi<4;mi++) af[mi]  = *(const s8v*)&As[(wm+mi*16+lr)*40 + lk];
        #pragma unroll
        for (int ni=0;ni<4;ni++) bfr[ni] = *(const s8v*)&Bs[(wn+ni*16+lr)*40 + lk];
        #pragma unroll
        for (int mi=0;mi<4;mi++)
          #pragma unroll
          for (int ni=0;ni<4;ni++)
            acc[mi][ni] = __builtin_amdgcn_mfma_f32_16x16x32_bf16(af[mi], bfr[ni], acc[mi][ni], 0,0,0);
        __syncthreads();
    }

    #pragma unroll
    for (int mi=0;mi<4;mi++){
      #pragma unroll
      for (int ni=0;ni<4;ni++){
        int col = n0+wn+ni*16+lr;
        if (col >= N) continue;
        float bv_ = bias ? bias[col] : 0.0f;
        #pragma unroll
        for (int r=0;r<4;r++){
          int row = m0+wm+mi*16+lq*4+r;
          if (row >= M) continue;
          float x = acc[mi][ni][r] + bv_;
          if (EPIL == 0){
              float* C = (float*)P0;
              size_t base = (SPLITK>0) ? (size_t)z*(size_t)sC : 0;
              size_t grow = (SPLITK>0) ? (size_t)row : (size_t)z*M + row;
              C[base + grow*ldc + col] = x;
          } else if (EPIL == 1){
              x = (x>0.0f) ? x : 0.01f*x;
              if (row < 4096) ((ushort_t*)P0)[(size_t)row*KAB + col] = f2bf(x);
              else            ((ushort_t*)P1)[(size_t)(row-4096)*32 + col] = f2bf(x);
          } else if (EPIL == 5){
              int b2 = row>>10, rh = row&1023;
              if (col < 32){
                  // kSw[b][kt][nt][l][8]: key rh, k-col 'col'
                  int kt = rh>>7, nt_=(rh>>4)&7, lrK=rh&15, lqK=col>>3, e=col&7;
                  ((ushort_t*)P0)[((((size_t)b2*8+kt)*8+nt_)*64 + lqK*16+lrK)*8 + e] = f2bf(x);
              } else if (col < 302){
                  // vSw[b][c][nt][l][8]: key rh, v-dim vd
                  int vd = col-32;
                  int c = rh>>5, lqV=(rh>>3)&3, e=rh&7, nt=vd>>4, lrV=vd&15;
                  ((ushort_t*)P1)[((((size_t)b2*32+c)*18+nt)*64 + lqV*16+lrV)*8 + e] = f2bf(x);
              } else {
                  ((float*)P2)[(size_t)row*H4c + (col-302)] = x;
              }
          }
        }
      }
    }
}

// ---------------------------------------------------------------------------
// Fused attention v3: register logits, swizzled direct K/V fragment loads,
// in-register softmax, Pb LDS only for the P transpose. Grid (64, B), 256 thr.
// ---------------------------------------------------------------------------
__global__ __launch_bounds__(256)
void attn_fused_kernel(const ushort_t* __restrict__ no_prev, const ushort_t* __restrict__ u_embb,
                       const float* __restrict__ Wq, const float* __restrict__ bq,
                       const ushort_t* __restrict__ kSw, const ushort_t* __restrict__ vSw,
                       const int* __restrict__ divided, const float* __restrict__ hm1,
                       ushort_t* __restrict__ Abuf, float* __restrict__ hm23,
                       int t, int wr23)
{
    __shared__ ushort_t Pb[32*16*40];    // 40960 B: P bf16 [chunk][row][k]
    __shared__ ushort_t Qs[16*40];
    __shared__ float    mskS[1024];
    __shared__ float    redS[4][16];
    __shared__ float    hasS[4];
    float* qinS = (float*)Pb;            // [16][33] f32 (2112 B, dead before Pb written)
    float* WqS  = (float*)&Pb[1056];     // [32][33] f32

    const int rt = blockIdx.x;
    const int b  = blockIdx.y;
    const int tid = threadIdx.x;
    const int w = tid>>6, l = tid&63, lr = l&15, lq = l>>4;
    const int lk8 = lq*8;
    const int row0 = rt*16;
    const size_t gq = (size_t)b*Nc + row0;

    // mask + has23
    bool lany = false;
    #pragma unroll
    for (int c4=0;c4<4;c4++){
        int c = tid*4 + c4;
        const int* dv = divided + (((size_t)b*Tc + t)*Nc + c)*3;
        bool m23 = (dv[1]>0)||(dv[2]>0);
        mskS[c] = m23 ? 1.0f : 0.0f;
        lany |= m23;
    }
    bool wany = __any(lany);
    if (l==0) hasS[w] = wany ? 1.0f : 0.0f;

    // qin staging (m3 select) + Wq
    for (int i=tid;i<16*32;i+=256){
        int r = i>>5, j = i&31;
        int n = row0 + r;
        bool m3 = divided[(((size_t)b*Tc+t)*Nc+n)*3+2] > 0;
        qinS[r*33+j] = m3 ? b2f(u_embb[(size_t)n*GSc+j]) : b2f(no_prev[(gq+r)*GSc+j]);
    }
    for (int i=tid;i<32*32;i+=256){
        int j=i>>5, o=i&31;
        WqS[j*33+o] = Wq[(size_t)j*ATc+o];
    }
    __syncthreads();
    const bool has = (hasS[0]+hasS[1]+hasS[2]+hasS[3]) > 0.5f;

    // q = qin @ Wq + bq -> Qs bf16
    {
        int r = tid>>4, o2 = (tid&15)*2;
        float a0 = bq[o2], a1 = bq[o2+1];
        for (int j=0;j<32;j++){
            float q = qinS[r*33+j];
            a0 += q*WqS[j*33+o2];
            a1 += q*WqS[j*33+o2+1];
        }
        Qs[r*40+o2]   = f2bf(a0);
        Qs[r*40+o2+1] = f2bf(a1);
    }
    __syncthreads();

    // QK^T: direct swizzled fragment loads, logits in registers
    s8v af = *(const s8v*)&Qs[lr*40 + lk8];
    s8v kf[8][2];
    #pragma unroll
    for (int kt=0;kt<8;kt++)
      #pragma unroll
      for (int ni=0;ni<2;ni++)
        kf[kt][ni] = *(const s8v*)(kSw + ((((size_t)b*8+kt)*8 + (w*2+ni))*64 + l)*8);
    f4v qk[8][2];
    #pragma unroll
    for (int kt=0;kt<8;kt++)
      #pragma unroll
      for (int ni=0;ni<2;ni++){
        f4v zz = (f4v){0,0,0,0};
        qk[kt][ni] = __builtin_amdgcn_mfma_f32_16x16x32_bf16(af, kf[kt][ni], zz, 0,0,0);
      }

    // in-register masked softmax (rows lq*4+r2, cols kt*128+(w*2+ni)*16+lr)
    float rmax[4] = {-INFINITY,-INFINITY,-INFINITY,-INFINITY};
    #pragma unroll
    for (int kt=0;kt<8;kt++)
      #pragma unroll
      for (int ni=0;ni<2;ni++){
        int colb = kt*128 + (w*2+ni)*16 + lr;
        float mk = mskS[colb];
        #pragma unroll
        for (int r2=0;r2<4;r2++){
            float v = qk[kt][ni][r2]*INV_SQRT_AT_F;
            qk[kt][ni][r2] = v;
            if (mk > 0.5f) rmax[r2] = fmaxf(rmax[r2], v);
        }
      }
    #pragma unroll
    for (int o=1;o<16;o<<=1)
      #pragma unroll
      for (int r2=0;r2<4;r2++) rmax[r2] = fmaxf(rmax[r2], __shfl_xor(rmax[r2], o, 64));
    if (lr==0){
        #pragma unroll
        for (int r2=0;r2<4;r2++) redS[w][lq*4+r2] = rmax[r2];
    }
    __syncthreads();
    float gm[4], inv[4];
    #pragma unroll
    for (int r2=0;r2<4;r2++){
        float m = fmaxf(fmaxf(redS[0][lq*4+r2], redS[1][lq*4+r2]),
                        fmaxf(redS[2][lq*4+r2], redS[3][lq*4+r2]));
        gm[r2] = m;
    }
    float rs[4] = {0,0,0,0};
    #pragma unroll
    for (int kt=0;kt<8;kt++)
      #pragma unroll
      for (int ni=0;ni<2;ni++){
        int colb = kt*128 + (w*2+ni)*16 + lr;
        float mk = mskS[colb];
        #pragma unroll
        for (int r2=0;r2<4;r2++){
            float p = (mk > 0.5f) ? expf(qk[kt][ni][r2] - gm[r2]) : 0.0f;
            qk[kt][ni][r2] = p;
            rs[r2] += p;
        }
      }
    #pragma unroll
    for (int o=1;o<16;o<<=1)
      #pragma unroll
      for (int r2=0;r2<4;r2++) rs[r2] += __shfl_xor(rs[r2], o, 64);
    __syncthreads();
    if (lr==0){
        #pragma unroll
        for (int r2=0;r2<4;r2++) redS[w][lq*4+r2] = rs[r2];
    }
    __syncthreads();
    #pragma unroll
    for (int r2=0;r2<4;r2++){
        float s = redS[0][lq*4+r2] + redS[1][lq*4+r2] + redS[2][lq*4+r2] + redS[3][lq*4+r2];
        inv[r2] = has ? 1.0f/s : 0.0f;
    }

    // pack normalized P -> Pb [chunk=kt*4+w][row=lq*4+r2][k=ni*16+lr]
    #pragma unroll
    for (int kt=0;kt<8;kt++)
      #pragma unroll
      for (int ni=0;ni<2;ni++)
        #pragma unroll
        for (int r2=0;r2<4;r2++)
            Pb[(kt*4+w)*640 + (lq*4+r2)*40 + ni*16+lr] = f2bf(qk[kt][ni][r2]*inv[r2]);
    __syncthreads();

    // PV: A from Pb (LDS b128), B = direct swizzled vSw fragments. No barriers.
    f4v acc[5];
    #pragma unroll
    for (int j5=0;j5<5;j5++) acc[j5] = (f4v){0,0,0,0};
    for (int c=0;c<32;c++){
        s8v pa = *(const s8v*)&Pb[c*640 + lr*40 + lk8];
        #pragma unroll
        for (int j5=0;j5<5;j5++){
            int nt = w + 4*j5;
            if (nt < 18){
                s8v vf = *(const s8v*)(vSw + ((((size_t)b*32+c)*18 + nt)*64 + l)*8);
                acc[j5] = __builtin_amdgcn_mfma_f32_16x16x32_bf16(pa, vf, acc[j5], 0,0,0);
            }
        }
    }

    // epilogue: tanh + h-update
    #pragma unroll
    for (int j5=0;j5<5;j5++){
        int nt = w + 4*j5;
        if (nt >= 18) continue;
        int col = nt*16 + lr;
        if (col >= Hc) continue;
        #pragma unroll
        for (int r2=0;r2<4;r2++){
            int row16 = lq*4 + r2;
            size_t grow = gq + row16;
            int n = row0 + row16;
            const int* dv = divided + (((size_t)b*Tc + t)*Nc + n)*3;
            bool m1  = dv[0]>0;
            bool m23 = (dv[1]>0)||(dv[2]>0);
            float xt = tanhf(acc[j5][r2]);
            float hv = m23 ? xt : (m1 ? hm1[grow*Hc + col] : 0.0f);
            Abuf[grow*KAB + 32 + col] = f2bf(hv);
            if (wr23) hm23[grow*Hc + col] = xt;
        }
    }
}

// ---------------------------------------------------------------------------
// f32 tiled GEMM (final layer). ACT 3 = sigmoid.
// ---------------------------------------------------------------------------
template<int ACT>
__global__ __launch_bounds__(256)
void gemm_kernel(const float* __restrict__ A, const float* __restrict__ Bm,
                 const float* __restrict__ bias, float* __restrict__ C,
                 int M, int Nn, int K)
{
    constexpr int BM=64, BN=64, BK=16;
    __shared__ float As[BK][BM+4];
    __shared__ float Bs[BK][BN+4];
    const int row0 = blockIdx.y*BM, col0 = blockIdx.x*BN;
    const int tid = threadIdx.x;
    const int tr = (tid>>4)<<2;
    const int tc = (tid&15)<<2;
    const int ar = tid>>2;
    const int ac = (tid&3)<<2;
    const int br = tid>>4;
    const int bc = (tid&15)<<2;
    float acc[4][4] = {};
    for (int k0=0;k0<K;k0+=BK){
        #pragma unroll
        for (int i=0;i<4;i++){
            int gr=row0+ar, gc=k0+ac+i;
            As[ac+i][ar] = (gr<M && gc<K) ? A[(size_t)gr*K+gc] : 0.0f;
        }
        #pragma unroll
        for (int i=0;i<4;i++){
            int gr=k0+br, gc=col0+bc+i;
            Bs[br][bc+i] = (gr<K && gc<Nn) ? Bm[(size_t)gr*Nn+gc] : 0.0f;
        }
        __syncthreads();
        #pragma unroll
        for (int kk=0;kk<BK;kk++){
            float a0=As[kk][tr+0], a1=As[kk][tr+1], a2=As[kk][tr+2], a3=As[kk][tr+3];
            float b0=Bs[kk][tc+0], b1=Bs[kk][tc+1], b2=Bs[kk][tc+2], b3=Bs[kk][tc+3];
            acc[0][0]+=a0*b0; acc[0][1]+=a0*b1; acc[0][2]+=a0*b2; acc[0][3]+=a0*b3;
            acc[1][0]+=a1*b0; acc[1][1]+=a1*b1; acc[1][2]+=a1*b2; acc[1][3]+=a1*b3;
            acc[2][0]+=a2*b0; acc[2][1]+=a2*b1; acc[2][2]+=a2*b2; acc[2][3]+=a2*b3;
            acc[3][0]+=a3*b0; acc[3][1]+=a3*b1; acc[3][2]+=a3*b2; acc[3][3]+=a3*b3;
        }
        __syncthreads();
    }
    #pragma unroll
    for (int i=0;i<4;i++){
        int r=row0+tr+i; if (r>=M) continue;
        #pragma unroll
        for (int j=0;j<4;j++){
            int c=col0+tc+j; if (c>=Nn) continue;
            float x = acc[i][j];
            if (bias) x += bias[c];
            if (ACT==3) x = 1.0f/(1.0f+expf(-x));
            C[(size_t)r*Nn+c] = x;
        }
    }
}

// ---------------------------------------------------------------------------
// Prep: all weight conversions + zero-fills (cascading ranges).
// ---------------------------------------------------------------------------
#define PR0 32768LL     // u_embb
#define PR1 2048LL      // WgT [32][64]
#define PR3 442240LL    // WB [1382][320]
#define PR4 1382LL      // biasB
#define PR5 449280LL    // WTl [1080][416]
#define PR6 313344LL    // WhhRT [17][64][288]
#define PR7 73728LL     // zero hbLA+hbLB
#define PR8 36864LL     // zero cst
#define PR9 1310720LL   // zero Abuf [4096][320]
#define PR10 1179648LL  // zero vSw (covers pad rows)
#define PRTOT (PR0+PR1+PR3+PR4+PR5+PR6+PR7+PR8+PR9+PR10)

__global__ void prep_kernel(const float* __restrict__ u_emb,
                            const float* __restrict__ Wg,
                            const float* __restrict__ Wk, const float* __restrict__ Wv,
                            const float* __restrict__ gru_Wih, const float* __restrict__ gru_Whh,
                            const float* __restrict__ bk, const float* __restrict__ bv,
                            const float* __restrict__ gru_bih, const float* __restrict__ gru_bhh,
                            const float* __restrict__ lstm_Wih, const float* __restrict__ lstm_Whh,
                            ushort_t* u_embb, ushort_t* WgT,
                            ushort_t* WB, float* biasB, ushort_t* WTl, ushort_t* WhhRT,
                            ushort_t* hbLA, ushort_t* hbLB, float* cst, ushort_t* Abuf,
                            ushort_t* vSw)
{
    long long idx = (long long)blockIdx.x*256 + threadIdx.x;
    if (idx < PR0){ u_embb[idx] = f2bf(u_emb[idx]); return; } idx -= PR0;
    if (idx < PR1){ int n=(int)(idx>>6), k=(int)(idx&63);
        WgT[idx] = (k<CSc) ? f2bf(Wg[(size_t)k*GSc+n]) : (ushort_t)0; return; } idx -= PR1;
    if (idx < PR3){
        int n=(int)(idx/KAB), k=(int)(idx%KAB);
        float v = 0.0f;
        if (n < 32){            if (k<32) v = Wk[(size_t)k*ATc + n]; }
        else if (n < 302){      if (k<32) v = Wv[(size_t)k*Hc + (n-32)]; }
        else if (n < 572){ int j=n-302;
            if (k<32) v = gru_Wih[(size_t)k*H3c + j];
            else if (k<302) v = gru_Whh[(size_t)(k-32)*H3c + j]; }
        else if (n < 842){ int j=(n-572)+270;
            if (k<32) v = gru_Wih[(size_t)k*H3c + j];
            else if (k<302) v = gru_Whh[(size_t)(k-32)*H3c + j]; }
        else if (n < 1112){ int j=(n-842)+540;
            if (k<32) v = gru_Wih[(size_t)k*H3c + j]; }
        else { int j=(n-1112)+540;
            if (k>=32 && k<302) v = gru_Whh[(size_t)(k-32)*H3c + j]; }
        WB[idx] = f2bf(v); return; } idx -= PR3;
    if (idx < PR4){
        int n = (int)idx; float v;
        if (n < 32)        v = bk[n];
        else if (n < 302)  v = bv[n-32];
        else if (n < 572)  v = gru_bih[n-302] + gru_bhh[n-302];
        else if (n < 842)  v = gru_bih[(n-572)+270] + gru_bhh[(n-572)+270];
        else if (n < 1112) v = gru_bih[(n-842)+540];
        else               v = gru_bhh[(n-1112)+540];
        biasB[n] = v; return; } idx -= PR4;
    if (idx < PR5){ int n=(int)(idx/KPE), k=(int)(idx%KPE);
        WTl[idx] = (k<EDc) ? f2bf(lstm_Wih[(size_t)k*H4c+n]) : (ushort_t)0; return; } idx -= PR5;
    if (idx < PR6){
        int jg=(int)(idx/(64*288)); int r2=(int)(idx%(64*288));
        int n=r2/288, k=r2%288;
        int gate=n>>4, jj=n&15, j=jg*16+jj;
        WhhRT[idx] = (k<Hc && j<Hc) ? f2bf(lstm_Whh[(size_t)k*H4c + gate*Hc + j]) : (ushort_t)0;
        return; } idx -= PR6;
    if (idx < PR7){ if (idx < 36864) hbLA[idx] = 0; else hbLB[idx-36864] = 0; return; } idx -= PR7;
    if (idx < PR8){ cst[idx] = 0.0f; return; } idx -= PR8;
    if (idx < PR9){ Abuf[idx] = 0; return; } idx -= PR9;
    if (idx < PR10){ vSw[idx] = 0; }
}

// ---------------------------------------------------------------------------
// adj nonzero-list build (adj entries are exactly 0.0/1.0)
// ---------------------------------------------------------------------------
__global__ void nz_build_kernel(const float* __restrict__ adj, int* __restrict__ nzc,
                                int* __restrict__ nzidx)
{
    int n = blockIdx.x;
    __shared__ int cnt;
    if (threadIdx.x == 0) cnt = 0;
    __syncthreads();
    for (int k = threadIdx.x; k < Nc; k += 256){
        if (adj[(size_t)n*Nc + k] != 0.0f){
            int pos = atomicAdd(&cnt, 1);
            if (pos < NZCAP) nzidx[(size_t)n*NZCAP + pos] = k;
        }
    }
    __syncthreads();
    if (threadIdx.x == 0) nzc[n] = (cnt < NZCAP) ? cnt : NZCAP;
}

// ---------------------------------------------------------------------------
// Sparse S: S[n][b*CS+c] = sum_{k in nz(n)} cm(b,k)*c_emb[k][c] + nm(b,k)*n_emb[k][c]
// ---------------------------------------------------------------------------
__global__ __launch_bounds__(192)
void s_sparse_kernel(const int* __restrict__ code_x, const int* __restrict__ neighbors,
                     const float* __restrict__ c_emb, const float* __restrict__ n_emb,
                     const int* __restrict__ nzc, const int* __restrict__ nzidx,
                     int t, float* __restrict__ S)
{
    int n = blockIdx.x;
    int tid = threadIdx.x;
    int b = tid / CSc, c = tid % CSc;
    int cnt = nzc[n];
    float s = 0.0f;
    for (int i=0; i<cnt; i++){
        int k = nzidx[(size_t)n*NZCAP + i];
        int cm = code_x  [((size_t)b*Tc+t)*Nc + k];
        int nm = neighbors[((size_t)b*Tc+t)*Nc + k];
        float e = 0.0f;
        if (cm) e += c_emb[(size_t)k*CSc + c];
        if (nm) e += n_emb[(size_t)k*CSc + c];
        s += e;
    }
    S[(size_t)n*(Bc*CSc) + tid] = s;
}

// ---------------------------------------------------------------------------
// GRU combine (t>=1): gsum layout [r][1080] = r|z|in|hn
// ---------------------------------------------------------------------------
__global__ void gru_combine_kernel(const float* __restrict__ gsum, const ushort_t* __restrict__ Abuf,
                                   float* __restrict__ hm1)
{
    int r = blockIdx.x;
    const float* G = gsum + (size_t)r*H4c;
    for (int j = threadIdx.x; j < Hc; j += blockDim.x){
        float rg = sigmoid_f(G[j]);
        float zg = sigmoid_f(G[270+j]);
        float ng = tanhf(G[540+j] + rg*G[810+j]);
        float h  = b2f(Abuf[(size_t)r*KAB + 32 + j]);
        hm1[(size_t)r*Hc + j] = (1.0f-zg)*ng + zg*h;
    }
}

// t=0: h=0; write h_new = m1 ? (1-z)*n : 0 directly into Abuf
__global__ void gru_combine_t0_kernel(const float* __restrict__ gsum, const int* __restrict__ divided,
                                      ushort_t* __restrict__ Abuf)
{
    int r = blockIdx.x;
    int b = r >> 10, n = r & 1023;
    bool m1 = divided[(((size_t)b*Tc+0)*Nc+n)*3 + 0] > 0;
    const float* G = gsum + (size_t)r*H4c;
    for (int j = threadIdx.x; j < Hc; j += blockDim.x){
        float rg = sigmoid_f(G[j]);
        float zg = sigmoid_f(G[270+j]);
        float ng = tanhf(G[540+j] + rg*G[810+j]);
        float hv = (1.0f-zg)*ng;
        Abuf[(size_t)r*KAB + 32 + j] = m1 ? f2bf(hv) : (ushort_t)0;
    }
}

// ---------------------------------------------------------------------------
// out_last reduction (t=5), coalesced
// ---------------------------------------------------------------------------
__global__ __launch_bounds__(320)
void outlast_partial_kernel(const int* __restrict__ divided,
                            const float* __restrict__ hm1, const float* __restrict__ hm23,
                            float* __restrict__ part1, float* __restrict__ part23)
{
    int nc = blockIdx.x, b = blockIdx.y;
    int j = threadIdx.x;
    if (j >= Hc) return;
    float m1v = -INFINITY, m23v = -INFINITY;
    #pragma unroll 4
    for (int n = nc*32; n < nc*32+32; n++){
        const int* dv = divided + (((size_t)b*Tc + (Tc-1))*Nc + n)*3;
        bool m1  = dv[0] > 0;
        bool m23 = (dv[1] > 0) || (dv[2] > 0);
        size_t o = ((size_t)b*Nc+n)*Hc + j;
        if (m1)  m1v  = fmaxf(m1v,  hm1[o]);
        if (m23) m23v = fmaxf(m23v, hm23[o]);
    }
    part1 [((size_t)b*32+nc)*320 + j] = m1v;
    part23[((size_t)b*32+nc)*320 + j] = m23v;
}

__global__ __launch_bounds__(320)
void outlast_combine_kernel(const float* __restrict__ part1, const float* __restrict__ part23,
                            float* __restrict__ outlast)
{
    int b = blockIdx.x; int j = threadIdx.x;
    if (j >= Hc) return;
    float a = -INFINITY, c = -INFINITY;
    for (int nc=0;nc<32;nc++){
        a = fmaxf(a, part1 [((size_t)b*32+nc)*320 + j]);
        c = fmaxf(c, part23[((size_t)b*32+nc)*320 + j]);
    }
    outlast[(size_t)b*Hc + j] = (a==-INFINITY ? 0.0f : a) + (c==-INFINITY ? 0.0f : c);
}

// ---------------------------------------------------------------------------
// LSTM MFMA step: 68 blocks = 4 cellgroups(32) x 17 jgroups(16 j-cols)
// ---------------------------------------------------------------------------
__global__ __launch_bounds__(256)
void lstm_step_mfma(const float* __restrict__ gx,
                    const ushort_t* __restrict__ WhhRT,
                    const ushort_t* __restrict__ hb_in,
                    ushort_t* __restrict__ hb_out,
                    float* __restrict__ cst,
                    float* __restrict__ hev_out)
{
    int cg = blockIdx.x & 3, jg = blockIdx.x >> 2;
    int tid = threadIdx.x;
    int w = tid>>6, l = tid&63;
    int mi = w>>1, ni0 = (w&1)*2;
    int arow = cg*32 + mi*16 + (l&15);
    int koff = (l>>4)*8;
    const ushort_t* Wb = WhhRT + (size_t)jg*64*288;

    f4v acc0 = (f4v){0,0,0,0}, acc1 = (f4v){0,0,0,0};
    #pragma unroll
    for (int k0=0;k0<288;k0+=32){
        s8v a  = *(const s8v*)(hb_in + (size_t)arow*288 + k0 + koff);
        s8v b0 = *(const s8v*)(Wb + (size_t)(ni0*16 + (l&15))*288 + k0 + koff);
        s8v b1 = *(const s8v*)(Wb + (size_t)((ni0+1)*16 + (l&15))*288 + k0 + koff);
        acc0 = __builtin_amdgcn_mfma_f32_16x16x32_bf16(a, b0, acc0, 0,0,0);
        acc1 = __builtin_amdgcn_mfma_f32_16x16x32_bf16(a, b1, acc1, 0,0,0);
    }
    __shared__ float gs[32][64];
    int crow = mi*16 + (l>>4)*4;
    int ccol = l&15;
    #pragma unroll
    for (int r=0;r<4;r++){
        gs[crow+r][ni0*16 + ccol]     = acc0[r];
        gs[crow+r][(ni0+1)*16 + ccol] = acc1[r];
    }
    __syncthreads();
    #pragma unroll
    for (int p=0;p<2;p++){
        int idx = tid + p*256;
        int cl = idx>>4, jj = idx&15;
        int j = jg*16 + jj;
        if (j < Hc){
            int cell = cg*32 + cl;
            const float* g = gx + (size_t)cell*H4c;
            float ig = sigmoid_f(gs[cl][jj]      + g[j]);
            float fg = sigmoid_f(gs[cl][16+jj]   + g[Hc+j]);
            float gg = tanhf    (gs[cl][32+jj]   + g[2*Hc+j]);
            float og = sigmoid_f(gs[cl][48+jj]   + g[3*Hc+j]);
            size_t co = (size_t)cell*288 + j;
            float cn = fg*cst[co] + ig*gg;
            cst[co] = cn;
            float hn = og*tanhf(cn);
            hb_out[co] = f2bf(hn);
            if (hev_out) hev_out[(size_t)cell*Hc + j] = hn;
        }
    }
}

// ---------------------------------------------------------------------------
// heads: wdc + dp_attention over [outlast ; hev] -> o1 (o2 == o1)
// ---------------------------------------------------------------------------
__global__ __launch_bounds__(256)
void heads_kernel(const float* __restrict__ outlast, const float* __restrict__ hev,
                  const float* __restrict__ Wd, const float* __restrict__ bd,
                  const float* __restrict__ ctx, float* __restrict__ o1)
{
    int b = blockIdx.x, tid = threadIdx.x;
    __shared__ float wdc[Hc+1];
    __shared__ float sc[Ec+1];
    for (int j=tid;j<Hc;j+=256){
        float s = 0.0f;
        for (int d=0;d<DAc;d++) s += Wd[(size_t)j*DAc+d]*ctx[d];
        wdc[j] = s;
    }
    if (tid == 255){
        float s = 0.0f;
        for (int d=0;d<DAc;d++) s += bd[d]*ctx[d];
        wdc[Hc] = s;
    }
    __syncthreads();
    if (tid < Ec+1){
        const float* x = (tid==0) ? (outlast + (size_t)b*Hc)
                                  : (hev + ((size_t)b*Ec + tid-1)*Hc);
        float s = wdc[Hc];
        for (int j=0;j<Hc;j++) s += x[j]*wdc[j];
        sc[tid] = s;
    }
    __syncthreads();
    if (tid == 0){
        float m = -INFINITY;
        for (int s=0;s<Ec+1;s++) m = fmaxf(m, sc[s]);
        float sum = 0.0f;
        for (int s=0;s<Ec+1;s++){ sc[s] = expf(sc[s]-m); sum += sc[s]; }
        float inv = 1.0f/sum;
        for (int s=0;s<Ec+1;s++) sc[s] *= inv;
    }
    __syncthreads();
    for (int j=tid;j<Hc;j+=256){
        float acc = sc[0]*outlast[(size_t)b*Hc + j];
        for (int e=0;e<Ec;e++) acc += sc[1+e]*hev[((size_t)b*Ec+e)*Hc + j];
        o1[(size_t)b*Hc + j] = acc;
    }
}

// ---------------------------------------------------------------------------
extern "C" void kernel_launch(void* const* d_in, const int* in_sizes, int n_in,
                              void* d_out, int out_size, void* d_ws, size_t ws_size,
                              hipStream_t stream)
{
    const int*   code_x    = (const int*)d_in[0];
    const int*   divided   = (const int*)d_in[1];
    const int*   neighbors = (const int*)d_in[2];
    const int*   events    = (const int*)d_in[4];
    const float* c_emb     = (const float*)d_in[5];
    const float* n_emb     = (const float*)d_in[6];
    const float* u_emb     = (const float*)d_in[7];
    const float* adj       = (const float*)d_in[8];
    const float* Wg        = (const float*)d_in[9];
    const float* bg        = (const float*)d_in[10];
    const float* gru_Wih   = (const float*)d_in[11];
    const float* gru_Whh   = (const float*)d_in[12];
    const float* gru_bih   = (const float*)d_in[13];
    const float* gru_bhh   = (const float*)d_in[14];
    const float* Wq        = (const float*)d_in[15];
    const float* bq        = (const float*)d_in[16];
    const float* Wk        = (const float*)d_in[17];
    const float* bk        = (const float*)d_in[18];
    const float* Wv        = (const float*)d_in[19];
    const float* bv        = (const float*)d_in[20];
    const float* Wd        = (const float*)d_in[21];
    const float* bd        = (const float*)d_in[22];
    const float* ctx       = (const float*)d_in[23];
    const float* Eemb      = (const float*)d_in[24];
    const float* lstm_Wih  = (const float*)d_in[25];
    const float* lstm_Whh  = (const float*)d_in[26];
    const float* lstm_b    = (const float*)d_in[27];
    const float* Wc        = (const float*)d_in[28];
    const float* bc        = (const float*)d_in[29];
    float* out = (float*)d_out;

    float* ws = (float*)d_ws;
    size_t off = 0;
    auto alloc = [&](size_t n){ n = (n+7)&~(size_t)7; float* p = ws + off; off += n; return p; };
    auto allocU = [&](size_t n){ return (ushort_t*)alloc((n+1)/2); };

    float* hm1     = alloc((size_t)Bc*Nc*Hc);
    float* hm23    = alloc((size_t)Bc*Nc*Hc);
    float* S       = alloc((size_t)Nc*Bc*CSc);
    float* gsum    = alloc((size_t)Bc*Nc*H4c);          // also gatesx (lstm) alias
    ushort_t* Abuf  = allocU((size_t)Bc*Nc*KAB);        // [4096][320]: co | h | pad
    ushort_t* noA   = allocU((size_t)Bc*Nc*GSc);
    ushort_t* noB   = allocU((size_t)Bc*Nc*GSc);
    ushort_t* kSw   = allocU((size_t)Bc*Nc*ATc);        // swizzled K fragments
    ushort_t* vSw   = allocU((size_t)Bc*32*18*64*8);    // swizzled V fragments (incl pad)
    ushort_t* u_embb= allocU((size_t)Nc*GSc);
    ushort_t* WgT   = allocU((size_t)GSc*KPG);
    ushort_t* WB    = allocU((size_t)NCMB*KAB);
    ushort_t* WTl   = allocU((size_t)H4c*KPE);
    ushort_t* WhhRT = allocU((size_t)17*64*288);
    ushort_t* hbLA  = allocU((size_t)BEc*288);
    ushort_t* hbLB  = allocU((size_t)BEc*288);
    float* cst     = alloc((size_t)BEc*288);
    float* biasB   = alloc((size_t)NCMB);
    int*   nzc     = (int*)alloc((size_t)Nc);
    int*   nzidx   = (int*)alloc((size_t)Nc*NZCAP);
    float* outlast = alloc((size_t)Bc*Hc);
    float* o1      = alloc((size_t)Bc*Hc);
    float* hev     = alloc((size_t)BEc*Hc);
    float* part1   = alloc((size_t)Bc*32*320);
    float* part23  = alloc((size_t)Bc*32*320);

    float* gatesx  = gsum;     // lstm input gates alias (post-loop)
    (void)ws_size; (void)in_sizes; (void)n_in; (void)out_size;

    // ---- prep: conversions + zero fills; adj nz-lists ----
    {
        long long nb = (PRTOT + 255) / 256;
        prep_kernel<<<dim3((unsigned)nb), dim3(256), 0, stream>>>(
            u_emb, Wg, Wk, Wv, gru_Wih, gru_Whh, bk, bv, gru_bih, gru_bhh,
            lstm_Wih, lstm_Whh,
            u_embb, WgT, WB, biasB, WTl, WhhRT, hbLA, hbLB, cst, Abuf, vSw);
        nz_build_kernel<<<dim3(Nc), dim3(256), 0, stream>>>(adj, nzc, nzidx);
    }

    ushort_t* no_prev = noB;
    ushort_t* no_cur  = noA;
    for (int t=0; t<Tc; t++){
        s_sparse_kernel<<<dim3(Nc), dim3(192), 0, stream>>>(code_x, neighbors, c_emb, n_emb,
                                                            nzc, nzidx, t, S);
        // co|no = leaky((mask*(emb+S)) @ Wg + bg): A built on the fly (ASEL2)
        mfma_k<1,0,2><<<dim3(1,64,1),256,0,stream>>>(
            (const ushort_t*)c_emb, WgT, bg,
            Abuf, no_cur, (void*)n_emb, S, code_x, neighbors,
            2*Bc*Nc, GSc, KPG, 0, KPG, 0, 0,0,0, t);
        // combined k|v|gates = [co|h] @ WB + biasB  (k,v written pre-swizzled)
        mfma_k<5,0,0><<<dim3(11,32,1),256,0,stream>>>(
            Abuf, WB, biasB,
            kSw, vSw, gsum, nullptr, nullptr, nullptr,
            Bc*Nc, NCMB, KAB, KAB, KAB, 0, 0,0,0, 0);
        if (t == 0){
            gru_combine_t0_kernel<<<dim3(Bc*Nc), dim3(256), 0, stream>>>(gsum, divided, Abuf);
        } else {
            gru_combine_kernel<<<dim3(Bc*Nc), dim3(256), 0, stream>>>(gsum, Abuf, hm1);
            // fused attention v3
            attn_fused_kernel<<<dim3(64, Bc), dim3(256), 0, stream>>>(
                no_prev, u_embb, Wq, bq, kSw, vSw, divided, hm1,
                Abuf, hm23, t, (t == Tc-1) ? 1 : 0);
            if (t == Tc-1){
                outlast_partial_kernel<<<dim3(32, Bc), dim3(320), 0, stream>>>(divided, hm1, hm23, part1, part23);
                outlast_combine_kernel<<<dim3(Bc), dim3(320), 0, stream>>>(part1, part23, outlast);
            }
        }
        ushort_t* tmp = no_prev; no_prev = no_cur; no_cur = tmp;
    }

    // ---- LSTM over last-visit events (gather fused into A-staging, ASEL3) ----
    mfma_k<0,0,3><<<dim3(9,32,1),256,0,stream>>>(
        nullptr, WTl, lstm_b,
        gatesx, nullptr, nullptr, Eemb, events, nullptr,
        BEc*Lc, H4c, KPE, 0, KPE, H4c, 0,0,0, 0);
    {
        ushort_t* hin = hbLA; ushort_t* hout = hbLB;
        for (int l=0; l<Lc; l++){
            lstm_step_mfma<<<dim3(68), dim3(256), 0, stream>>>(
                gatesx + (size_t)l*BEc*H4c, WhhRT, hin, hout, cst,
                (l == Lc-1) ? hev : nullptr);
            ushort_t* tmp = hin; hin = hout; hout = tmp;
        }
    }

    // ---- heads ----
    heads_kernel<<<dim3(Bc), dim3(256), 0, stream>>>(outlast, hev, Wd, bd, ctx, o1);
    {
        dim3 grid((OUTc+63)/64, 1, 1);
        gemm_kernel<3><<<grid,dim3(256),0,stream>>>(o1, Wc, bc, out, Bc, OUTc, Hc);
    }
}

// Round 10
// 1044.975 us; speedup vs baseline: 1.2386x; 1.0093x over previous
//
#include <hip/hip_runtime.h>
#include <hip/hip_bf16.h>
#include <math.h>

// Problem constants
#define Bc   4
#define Tc   6
#define Nc   1024
#define CSc  48
#define GSc  32
#define Hc   270
#define ATc  32
#define DAc  64
#define Ec   32
#define Lc   32
#define EDc  400
#define OUTc 4000
#define H3c  810
#define H4c  1080
#define BEc  128
#define KPE  416    // ED padded
#define KPG  64     // CS padded
#define KAB  320    // Abuf K: 32 co + 270 h + 18 pad
#define NCMB 1382   // combined N: 32 k + 270 v + 270 r + 270 z + 270 in + 270 hn
#define NZCAP 96
#define INV_SQRT_AT_F 0.17677669529663687f

typedef unsigned short ushort_t;
using s8v  = __attribute__((ext_vector_type(8))) short;
using f4v  = __attribute__((ext_vector_type(4))) float;
using u16x8= __attribute__((ext_vector_type(8))) unsigned short;

__device__ __forceinline__ float sigmoid_f(float x){ return 1.0f/(1.0f+expf(-x)); }
__device__ __forceinline__ ushort_t f2bf(float x){
    __hip_bfloat16 b = __float2bfloat16(x);
    return *reinterpret_cast<ushort_t*>(&b);
}
__device__ __forceinline__ float b2f(ushort_t u){
    return __uint_as_float(((unsigned int)u)<<16);
}

// ---------------------------------------------------------------------------
// bf16 MFMA GEMM, 128x128 tile, 4 waves.
// EPIL 0: f32 store (+bias)
// EPIL 5: combined: col<32 -> kSw (swizzled frag layout); col<302 -> vSw
//         (swizzled frag layout); else gsum f32
// ASEL 3: lstm gather: PF=Eemb(f32), DV=events
// ---------------------------------------------------------------------------
template<int EPIL, int SPLITK, int ASEL>
__global__ __launch_bounds__(256)
void mfma_k(const ushort_t* __restrict__ A, const ushort_t* __restrict__ BT,
            const float* __restrict__ bias,
            void* __restrict__ P0, void* __restrict__ P1, void* __restrict__ P2,
            const float* __restrict__ PF, const int* __restrict__ DV,
            const int* __restrict__ DV2,
            int M, int N, int Kp, int lda, int ldb, int ldc,
            long long sA, long long sB, long long sC, int tpar)
{
    __shared__ ushort_t As[128*40];
    __shared__ ushort_t Bs[128*40];
    const int z = blockIdx.z;
    int kbeg = 0, kend = Kp;
    if (SPLITK > 0){
        int ks = Kp / SPLITK;
        kbeg = z*ks; kend = kbeg + ks;
    } else {
        if (ASEL == 0) A += (size_t)z * (size_t)sA;
        BT += (size_t)z * (size_t)sB;
    }
    const int m0 = blockIdx.y*128, n0 = blockIdx.x*128;
    const int tid = threadIdx.x;
    const int w = tid>>6, l = tid&63;
    const int wm = (w>>1)*64, wn = (w&1)*64;
    const int lr = l&15, lk = (l>>4)*8, lq = l>>4;
    const int srow = tid>>2, kseg = tid&3;

    f4v acc[4][4];
    #pragma unroll
    for (int mi=0;mi<4;mi++)
      #pragma unroll
      for (int ni=0;ni<4;ni++)
        acc[mi][ni] = (f4v){0.0f,0.0f,0.0f,0.0f};

    for (int k0=kbeg;k0<kend;k0+=32){
        #pragma unroll
        for (int i=0;i<2;i++){
            int row = srow + i*64;
            int ga = m0+row;
            uint4 va = make_uint4(0u,0u,0u,0u);
            if (ga < M){
                if (ASEL == 3){
                    int ll = ga >> 7, be = ga & 127; int b = be >> 5, e = be & 31;
                    int kk = k0 + kseg*8;
                    if (kk < EDc){
                        int ev = DV[(((size_t)b*Tc + (Tc-1))*Ec + e)*Lc + ll];
                        const float* src = PF + (size_t)ev*EDc + kk;
                        f4v e0 = *(const f4v*)src;
                        f4v e1 = *(const f4v*)(src + 4);
                        u16x8 tmp;
                        #pragma unroll
                        for (int j=0;j<4;j++) tmp[j]   = f2bf(e0[j]);
                        #pragma unroll
                        for (int j=0;j<4;j++) tmp[4+j] = f2bf(e1[j]);
                        va = *(uint4*)&tmp;
                    }
                } else {
                    va = *(const uint4*)(A + (size_t)ga*lda + k0 + kseg*8);
                }
            }
            *(uint4*)&As[row*40 + kseg*8] = va;
            int gb = n0+row;
            uint4 vb = make_uint4(0u,0u,0u,0u);
            if (gb < N) vb = *(const uint4*)(BT + (size_t)gb*ldb + k0 + kseg*8);
            *(uint4*)&Bs[row*40 + kseg*8] = vb;
        }
        __syncthreads();
        s8v af[4], bfr[4];
        #pragma unroll
        for (int mi=0;mi<4;mi++) af[mi]  = *(const s8v*)&As[(wm+mi*16+lr)*40 + lk];
        #pragma unroll
        for (int ni=0;ni<4;ni++) bfr[ni] = *(const s8v*)&Bs[(wn+ni*16+lr)*40 + lk];
        #pragma unroll
        for (int mi=0;mi<4;mi++)
          #pragma unroll
          for (int ni=0;ni<4;ni++)
            acc[mi][ni] = __builtin_amdgcn_mfma_f32_16x16x32_bf16(af[mi], bfr[ni], acc[mi][ni], 0,0,0);
        __syncthreads();
    }

    #pragma unroll
    for (int mi=0;mi<4;mi++){
      #pragma unroll
      for (int ni=0;ni<4;ni++){
        int col = n0+wn+ni*16+lr;
        if (col >= N) continue;
        float bv_ = bias ? bias[col] : 0.0f;
        #pragma unroll
        for (int r=0;r<4;r++){
          int row = m0+wm+mi*16+lq*4+r;
          if (row >= M) continue;
          float x = acc[mi][ni][r] + bv_;
          if (EPIL == 0){
              float* C = (float*)P0;
              size_t base = (SPLITK>0) ? (size_t)z*(size_t)sC : 0;
              size_t grow = (SPLITK>0) ? (size_t)row : (size_t)z*M + row;
              C[base + grow*ldc + col] = x;
          } else if (EPIL == 5){
              int b2 = row>>10, rh = row&1023;
              if (col < 32){
                  // kSw[b][kt][nt][l][8]: key rh, k-col 'col'
                  int kt = rh>>7, nt_=(rh>>4)&7, lrK=rh&15, lqK=col>>3, e=col&7;
                  ((ushort_t*)P0)[((((size_t)b2*8+kt)*8+nt_)*64 + lqK*16+lrK)*8 + e] = f2bf(x);
              } else if (col < 302){
                  // vSw[b][c][nt][l][8]: key rh, v-dim vd
                  int vd = col-32;
                  int c = rh>>5, lqV=(rh>>3)&3, e=rh&7, nt=vd>>4, lrV=vd&15;
                  ((ushort_t*)P1)[((((size_t)b2*32+c)*18+nt)*64 + lqV*16+lrV)*8 + e] = f2bf(x);
              } else {
                  ((float*)P2)[(size_t)row*H4c + (col-302)] = x;
              }
          }
        }
      }
    }
}

// ---------------------------------------------------------------------------
// cono: co|no = leaky((mask*(emb+S)) @ Wg + bg). 1024 blocks, 4 (b,n) pairs
// per block (co+no share the S row), Wg in LDS. Writes Abuf co / no_cur bf16.
// ---------------------------------------------------------------------------
__global__ __launch_bounds__(256)
void cono_kernel(const int* __restrict__ code_x, const int* __restrict__ neighbors,
                 const float* __restrict__ c_emb, const float* __restrict__ n_emb,
                 const float* __restrict__ S, const float* __restrict__ Wg,
                 const float* __restrict__ bg, int t,
                 ushort_t* __restrict__ Abuf, ushort_t* __restrict__ no_cur)
{
    __shared__ float X[8][48];
    __shared__ float Wgs[48][32];
    __shared__ float bgs[32];
    int bk = blockIdx.x, tid = threadIdx.x;
    for (int i=tid;i<48*32;i+=256) Wgs[i>>5][i&31] = Wg[i];
    if (tid < 32) bgs[tid] = bg[tid];
    if (tid < 192){
        int q = tid/48, k = tid%48;
        int r = bk*4+q; int b = r>>10, n = r&1023;
        float cm = (float)code_x  [((size_t)b*Tc+t)*Nc + n];
        float nm = (float)neighbors[((size_t)b*Tc+t)*Nc + n];
        float s  = S[(size_t)n*(Bc*CSc) + b*CSc + k];
        X[q][k]   = cm*(c_emb[(size_t)n*CSc+k] + s);
        X[4+q][k] = nm*(n_emb[(size_t)n*CSc+k] + s);
    }
    __syncthreads();
    int slot = tid>>5, c = tid&31;
    float a = bgs[c];
    #pragma unroll
    for (int k=0;k<48;k++) a += X[slot][k]*Wgs[k][c];
    a = (a>0.0f) ? a : 0.01f*a;
    int r = bk*4 + (slot&3);
    if (slot < 4) Abuf[(size_t)r*KAB + c] = f2bf(a);
    else          no_cur[(size_t)r*GSc + c] = f2bf(a);
}

// ---------------------------------------------------------------------------
// Fused attention v4: 8 q-rows/block, grid (128, B) = 512 blocks (2/CU).
// Register logits, swizzled direct K/V fragment loads, in-register softmax.
// Writes Abuf-h only for m23 rows (gru_combine covers the rest; no hm1 read).
// ---------------------------------------------------------------------------
__global__ __launch_bounds__(256)
void attn_fused_kernel(const ushort_t* __restrict__ no_prev, const ushort_t* __restrict__ u_embb,
                       const float* __restrict__ Wq, const float* __restrict__ bq,
                       const ushort_t* __restrict__ kSw, const ushort_t* __restrict__ vSw,
                       const int* __restrict__ divided,
                       ushort_t* __restrict__ Abuf, float* __restrict__ hm23,
                       int t, int wr23)
{
    __shared__ ushort_t Pb[32*16*40];    // P bf16 [chunk][row][k] (rows 8..15 pad)
    __shared__ ushort_t Qs[16*40];       // rows 8..15 zero
    __shared__ float    mskS[1024];
    __shared__ float    redS[4][16];
    __shared__ float    hasS[4];
    float* qinS = (float*)Pb;            // [8][33] f32 (1056 B)
    float* WqS  = (float*)&Pb[1056];     // [32][33] f32 (byte 2112)

    const int rt = blockIdx.x;           // 0..127
    const int b  = blockIdx.y;
    const int tid = threadIdx.x;
    const int w = tid>>6, l = tid&63, lr = l&15, lq = l>>4;
    const int lk8 = lq*8;
    const int row0 = rt*8;
    const size_t gq = (size_t)b*Nc + row0;

    // mask + has23
    bool lany = false;
    #pragma unroll
    for (int c4=0;c4<4;c4++){
        int c = tid*4 + c4;
        const int* dv = divided + (((size_t)b*Tc + t)*Nc + c)*3;
        bool m23 = (dv[1]>0)||(dv[2]>0);
        mskS[c] = m23 ? 1.0f : 0.0f;
        lany |= m23;
    }
    bool wany = __any(lany);
    if (l==0) hasS[w] = wany ? 1.0f : 0.0f;

    // qin staging (m3 select) + Wq
    if (tid < 8*32){
        int r = tid>>5, j = tid&31;
        int n = row0 + r;
        bool m3 = divided[(((size_t)b*Tc+t)*Nc+n)*3+2] > 0;
        qinS[r*33+j] = m3 ? b2f(u_embb[(size_t)n*GSc+j]) : b2f(no_prev[(gq+r)*GSc+j]);
    }
    for (int i=tid;i<32*32;i+=256){
        int j=i>>5, o=i&31;
        WqS[j*33+o] = Wq[(size_t)j*ATc+o];
    }
    __syncthreads();
    const bool has = (hasS[0]+hasS[1]+hasS[2]+hasS[3]) > 0.5f;

    // q = qin @ Wq + bq -> Qs bf16 (rows 8..15 = 0)
    {
        int r = tid>>4, o2 = (tid&15)*2;
        float a0 = 0.0f, a1 = 0.0f;
        if (r < 8){
            a0 = bq[o2]; a1 = bq[o2+1];
            for (int j=0;j<32;j++){
                float q = qinS[r*33+j];
                a0 += q*WqS[j*33+o2];
                a1 += q*WqS[j*33+o2+1];
            }
        }
        Qs[r*40+o2]   = f2bf(a0);
        Qs[r*40+o2+1] = f2bf(a1);
    }
    __syncthreads();

    // QK^T: direct swizzled fragment loads, logits in registers
    s8v af = *(const s8v*)&Qs[lr*40 + lk8];
    s8v kf[8][2];
    #pragma unroll
    for (int kt=0;kt<8;kt++)
      #pragma unroll
      for (int ni=0;ni<2;ni++)
        kf[kt][ni] = *(const s8v*)(kSw + ((((size_t)b*8+kt)*8 + (w*2+ni))*64 + l)*8);
    f4v qk[8][2];
    #pragma unroll
    for (int kt=0;kt<8;kt++)
      #pragma unroll
      for (int ni=0;ni<2;ni++){
        f4v zz = (f4v){0,0,0,0};
        qk[kt][ni] = __builtin_amdgcn_mfma_f32_16x16x32_bf16(af, kf[kt][ni], zz, 0,0,0);
      }

    // in-register masked softmax (rows lq*4+r2, cols kt*128+(w*2+ni)*16+lr)
    float rmax[4] = {-INFINITY,-INFINITY,-INFINITY,-INFINITY};
    #pragma unroll
    for (int kt=0;kt<8;kt++)
      #pragma unroll
      for (int ni=0;ni<2;ni++){
        int colb = kt*128 + (w*2+ni)*16 + lr;
        float mk = mskS[colb];
        #pragma unroll
        for (int r2=0;r2<4;r2++){
            float v = qk[kt][ni][r2]*INV_SQRT_AT_F;
            qk[kt][ni][r2] = v;
            if (mk > 0.5f) rmax[r2] = fmaxf(rmax[r2], v);
        }
      }
    #pragma unroll
    for (int o=1;o<16;o<<=1)
      #pragma unroll
      for (int r2=0;r2<4;r2++) rmax[r2] = fmaxf(rmax[r2], __shfl_xor(rmax[r2], o, 64));
    if (lr==0){
        #pragma unroll
        for (int r2=0;r2<4;r2++) redS[w][lq*4+r2] = rmax[r2];
    }
    __syncthreads();
    float gm[4], inv[4];
    #pragma unroll
    for (int r2=0;r2<4;r2++){
        float m = fmaxf(fmaxf(redS[0][lq*4+r2], redS[1][lq*4+r2]),
                        fmaxf(redS[2][lq*4+r2], redS[3][lq*4+r2]));
        gm[r2] = m;
    }
    float rs[4] = {0,0,0,0};
    #pragma unroll
    for (int kt=0;kt<8;kt++)
      #pragma unroll
      for (int ni=0;ni<2;ni++){
        int colb = kt*128 + (w*2+ni)*16 + lr;
        float mk = mskS[colb];
        #pragma unroll
        for (int r2=0;r2<4;r2++){
            float p = (mk > 0.5f) ? expf(qk[kt][ni][r2] - gm[r2]) : 0.0f;
            qk[kt][ni][r2] = p;
            rs[r2] += p;
        }
      }
    #pragma unroll
    for (int o=1;o<16;o<<=1)
      #pragma unroll
      for (int r2=0;r2<4;r2++) rs[r2] += __shfl_xor(rs[r2], o, 64);
    __syncthreads();
    if (lr==0){
        #pragma unroll
        for (int r2=0;r2<4;r2++) redS[w][lq*4+r2] = rs[r2];
    }
    __syncthreads();
    #pragma unroll
    for (int r2=0;r2<4;r2++){
        float s = redS[0][lq*4+r2] + redS[1][lq*4+r2] + redS[2][lq*4+r2] + redS[3][lq*4+r2];
        inv[r2] = has ? 1.0f/s : 0.0f;
    }

    // pack normalized P -> Pb [chunk=kt*4+w][row=lq*4+r2][k=ni*16+lr]
    #pragma unroll
    for (int kt=0;kt<8;kt++)
      #pragma unroll
      for (int ni=0;ni<2;ni++)
        #pragma unroll
        for (int r2=0;r2<4;r2++)
            Pb[(kt*4+w)*640 + (lq*4+r2)*40 + ni*16+lr] = f2bf(qk[kt][ni][r2]*inv[r2]);
    __syncthreads();

    // PV: A from Pb (LDS b128), B = direct swizzled vSw fragments. No barriers.
    f4v acc[5];
    #pragma unroll
    for (int j5=0;j5<5;j5++) acc[j5] = (f4v){0,0,0,0};
    #pragma unroll 4
    for (int c=0;c<32;c++){
        s8v pa = *(const s8v*)&Pb[c*640 + lr*40 + lk8];
        #pragma unroll
        for (int j5=0;j5<5;j5++){
            int nt = w + 4*j5;
            if (nt < 18){
                s8v vf = *(const s8v*)(vSw + ((((size_t)b*32+c)*18 + nt)*64 + l)*8);
                acc[j5] = __builtin_amdgcn_mfma_f32_16x16x32_bf16(pa, vf, acc[j5], 0,0,0);
            }
        }
    }

    // epilogue: tanh; write Abuf-h only for m23 rows; hm23 (all rows) at t=5
    #pragma unroll
    for (int j5=0;j5<5;j5++){
        int nt = w + 4*j5;
        if (nt >= 18) continue;
        int col = nt*16 + lr;
        if (col >= Hc) continue;
        #pragma unroll
        for (int r2=0;r2<4;r2++){
            int row16 = lq*4 + r2;
            if (row16 >= 8) continue;
            size_t grow = gq + row16;
            int n = row0 + row16;
            const int* dv = divided + (((size_t)b*Tc + t)*Nc + n)*3;
            bool m23 = (dv[1]>0)||(dv[2]>0);
            float xt = tanhf(acc[j5][r2]);
            if (m23) Abuf[grow*KAB + 32 + col] = f2bf(xt);
            if (wr23) hm23[grow*Hc + col] = xt;
        }
    }
}

// ---------------------------------------------------------------------------
// f32 tiled GEMM (final layer). ACT 3 = sigmoid.
// ---------------------------------------------------------------------------
template<int ACT>
__global__ __launch_bounds__(256)
void gemm_kernel(const float* __restrict__ A, const float* __restrict__ Bm,
                 const float* __restrict__ bias, float* __restrict__ C,
                 int M, int Nn, int K)
{
    constexpr int BM=64, BN=64, BK=16;
    __shared__ float As[BK][BM+4];
    __shared__ float Bs[BK][BN+4];
    const int row0 = blockIdx.y*BM, col0 = blockIdx.x*BN;
    const int tid = threadIdx.x;
    const int tr = (tid>>4)<<2;
    const int tc = (tid&15)<<2;
    const int ar = tid>>2;
    const int ac = (tid&3)<<2;
    const int br = tid>>4;
    const int bc = (tid&15)<<2;
    float acc[4][4] = {};
    for (int k0=0;k0<K;k0+=BK){
        #pragma unroll
        for (int i=0;i<4;i++){
            int gr=row0+ar, gc=k0+ac+i;
            As[ac+i][ar] = (gr<M && gc<K) ? A[(size_t)gr*K+gc] : 0.0f;
        }
        #pragma unroll
        for (int i=0;i<4;i++){
            int gr=k0+br, gc=col0+bc+i;
            Bs[br][bc+i] = (gr<K && gc<Nn) ? Bm[(size_t)gr*Nn+gc] : 0.0f;
        }
        __syncthreads();
        #pragma unroll
        for (int kk=0;kk<BK;kk++){
            float a0=As[kk][tr+0], a1=As[kk][tr+1], a2=As[kk][tr+2], a3=As[kk][tr+3];
            float b0=Bs[kk][tc+0], b1=Bs[kk][tc+1], b2=Bs[kk][tc+2], b3=Bs[kk][tc+3];
            acc[0][0]+=a0*b0; acc[0][1]+=a0*b1; acc[0][2]+=a0*b2; acc[0][3]+=a0*b3;
            acc[1][0]+=a1*b0; acc[1][1]+=a1*b1; acc[1][2]+=a1*b2; acc[1][3]+=a1*b3;
            acc[2][0]+=a2*b0; acc[2][1]+=a2*b1; acc[2][2]+=a2*b2; acc[2][3]+=a2*b3;
            acc[3][0]+=a3*b0; acc[3][1]+=a3*b1; acc[3][2]+=a3*b2; acc[3][3]+=a3*b3;
        }
        __syncthreads();
    }
    #pragma unroll
    for (int i=0;i<4;i++){
        int r=row0+tr+i; if (r>=M) continue;
        #pragma unroll
        for (int j=0;j<4;j++){
            int c=col0+tc+j; if (c>=Nn) continue;
            float x = acc[i][j];
            if (bias) x += bias[c];
            if (ACT==3) x = 1.0f/(1.0f+expf(-x));
            C[(size_t)r*Nn+c] = x;
        }
    }
}

// ---------------------------------------------------------------------------
// Prep: all weight conversions + zero-fills (cascading ranges).
// ---------------------------------------------------------------------------
#define PR0 32768LL     // u_embb
#define PR1 2048LL      // WgT (legacy, unused)
#define PR3 442240LL    // WB [1382][320]
#define PR4 1382LL      // biasB
#define PR5 449280LL    // WTl [1080][416]
#define PR6 313344LL    // WhhRT [17][64][288]
#define PR7 73728LL     // zero hbLA+hbLB
#define PR8 36864LL     // zero cst
#define PR9 1310720LL   // zero Abuf [4096][320]
#define PR10 1179648LL  // zero vSw (covers pad rows)
#define PRTOT (PR0+PR1+PR3+PR4+PR5+PR6+PR7+PR8+PR9+PR10)

__global__ void prep_kernel(const float* __restrict__ u_emb,
                            const float* __restrict__ Wg,
                            const float* __restrict__ Wk, const float* __restrict__ Wv,
                            const float* __restrict__ gru_Wih, const float* __restrict__ gru_Whh,
                            const float* __restrict__ bk, const float* __restrict__ bv,
                            const float* __restrict__ gru_bih, const float* __restrict__ gru_bhh,
                            const float* __restrict__ lstm_Wih, const float* __restrict__ lstm_Whh,
                            ushort_t* u_embb, ushort_t* WgT,
                            ushort_t* WB, float* biasB, ushort_t* WTl, ushort_t* WhhRT,
                            ushort_t* hbLA, ushort_t* hbLB, float* cst, ushort_t* Abuf,
                            ushort_t* vSw)
{
    long long idx = (long long)blockIdx.x*256 + threadIdx.x;
    if (idx < PR0){ u_embb[idx] = f2bf(u_emb[idx]); return; } idx -= PR0;
    if (idx < PR1){ int n=(int)(idx>>6), k=(int)(idx&63);
        WgT[idx] = (k<CSc) ? f2bf(Wg[(size_t)k*GSc+n]) : (ushort_t)0; return; } idx -= PR1;
    if (idx < PR3){
        int n=(int)(idx/KAB), k=(int)(idx%KAB);
        float v = 0.0f;
        if (n < 32){            if (k<32) v = Wk[(size_t)k*ATc + n]; }
        else if (n < 302){      if (k<32) v = Wv[(size_t)k*Hc + (n-32)]; }
        else if (n < 572){ int j=n-302;
            if (k<32) v = gru_Wih[(size_t)k*H3c + j];
            else if (k<302) v = gru_Whh[(size_t)(k-32)*H3c + j]; }
        else if (n < 842){ int j=(n-572)+270;
            if (k<32) v = gru_Wih[(size_t)k*H3c + j];
            else if (k<302) v = gru_Whh[(size_t)(k-32)*H3c + j]; }
        else if (n < 1112){ int j=(n-842)+540;
            if (k<32) v = gru_Wih[(size_t)k*H3c + j]; }
        else { int j=(n-1112)+540;
            if (k>=32 && k<302) v = gru_Whh[(size_t)(k-32)*H3c + j]; }
        WB[idx] = f2bf(v); return; } idx -= PR3;
    if (idx < PR4){
        int n = (int)idx; float v;
        if (n < 32)        v = bk[n];
        else if (n < 302)  v = bv[n-32];
        else if (n < 572)  v = gru_bih[n-302] + gru_bhh[n-302];
        else if (n < 842)  v = gru_bih[(n-572)+270] + gru_bhh[(n-572)+270];
        else if (n < 1112) v = gru_bih[(n-842)+540];
        else               v = gru_bhh[(n-1112)+540];
        biasB[n] = v; return; } idx -= PR4;
    if (idx < PR5){ int n=(int)(idx/KPE), k=(int)(idx%KPE);
        WTl[idx] = (k<EDc) ? f2bf(lstm_Wih[(size_t)k*H4c+n]) : (ushort_t)0; return; } idx -= PR5;
    if (idx < PR6){
        int jg=(int)(idx/(64*288)); int r2=(int)(idx%(64*288));
        int n=r2/288, k=r2%288;
        int gate=n>>4, jj=n&15, j=jg*16+jj;
        WhhRT[idx] = (k<Hc && j<Hc) ? f2bf(lstm_Whh[(size_t)k*H4c + gate*Hc + j]) : (ushort_t)0;
        return; } idx -= PR6;
    if (idx < PR7){ if (idx < 36864) hbLA[idx] = 0; else hbLB[idx-36864] = 0; return; } idx -= PR7;
    if (idx < PR8){ cst[idx] = 0.0f; return; } idx -= PR8;
    if (idx < PR9){ Abuf[idx] = 0; return; } idx -= PR9;
    if (idx < PR10){ vSw[idx] = 0; }
}

// ---------------------------------------------------------------------------
// adj nonzero-list build (adj entries are exactly 0.0/1.0)
// ---------------------------------------------------------------------------
__global__ void nz_build_kernel(const float* __restrict__ adj, int* __restrict__ nzc,
                                int* __restrict__ nzidx)
{
    int n = blockIdx.x;
    __shared__ int cnt;
    if (threadIdx.x == 0) cnt = 0;
    __syncthreads();
    for (int k = threadIdx.x; k < Nc; k += 256){
        if (adj[(size_t)n*Nc + k] != 0.0f){
            int pos = atomicAdd(&cnt, 1);
            if (pos < NZCAP) nzidx[(size_t)n*NZCAP + pos] = k;
        }
    }
    __syncthreads();
    if (threadIdx.x == 0) nzc[n] = (cnt < NZCAP) ? cnt : NZCAP;
}

// ---------------------------------------------------------------------------
// Sparse S: S[n][b*CS+c] = sum_{k in nz(n)} cm(b,k)*c_emb[k][c] + nm(b,k)*n_emb[k][c]
// ---------------------------------------------------------------------------
__global__ __launch_bounds__(192)
void s_sparse_kernel(const int* __restrict__ code_x, const int* __restrict__ neighbors,
                     const float* __restrict__ c_emb, const float* __restrict__ n_emb,
                     const int* __restrict__ nzc, const int* __restrict__ nzidx,
                     int t, float* __restrict__ S)
{
    int n = blockIdx.x;
    int tid = threadIdx.x;
    int b = tid / CSc, c = tid % CSc;
    int cnt = nzc[n];
    float s = 0.0f;
    for (int i=0; i<cnt; i++){
        int k = nzidx[(size_t)n*NZCAP + i];
        int cm = code_x  [((size_t)b*Tc+t)*Nc + k];
        int nm = neighbors[((size_t)b*Tc+t)*Nc + k];
        float e = 0.0f;
        if (cm) e += c_emb[(size_t)k*CSc + c];
        if (nm) e += n_emb[(size_t)k*CSc + c];
        s += e;
    }
    S[(size_t)n*(Bc*CSc) + tid] = s;
}

// ---------------------------------------------------------------------------
// GRU combine (t>=1): gsum layout [r][1080] = r|z|in|hn.
// Writes Abuf-h (bf16) for !m23 rows; hm1 f32 only at t==Tc-1.
// ---------------------------------------------------------------------------
__global__ void gru_combine_kernel(const float* __restrict__ gsum, ushort_t* __restrict__ Abuf,
                                   const int* __restrict__ divided, float* __restrict__ hm1,
                                   int t)
{
    int r = blockIdx.x;
    int b = r >> 10, n = r & 1023;
    const int* dv = divided + (((size_t)b*Tc+t)*Nc+n)*3;
    bool m1  = dv[0] > 0;
    bool m23 = (dv[1] > 0) || (dv[2] > 0);
    bool last = (t == Tc-1);
    const float* G = gsum + (size_t)r*H4c;
    for (int j = threadIdx.x; j < Hc; j += blockDim.x){
        float rg = sigmoid_f(G[j]);
        float zg = sigmoid_f(G[270+j]);
        float ng = tanhf(G[540+j] + rg*G[810+j]);
        float h  = b2f(Abuf[(size_t)r*KAB + 32 + j]);
        float hv = (1.0f-zg)*ng + zg*h;
        if (!m23) Abuf[(size_t)r*KAB + 32 + j] = m1 ? f2bf(hv) : (ushort_t)0;
        if (last) hm1[(size_t)r*Hc + j] = hv;
    }
}

// t=0: h=0; write h_new = m1 ? (1-z)*n : 0 directly into Abuf
__global__ void gru_combine_t0_kernel(const float* __restrict__ gsum, const int* __restrict__ divided,
                                      ushort_t* __restrict__ Abuf)
{
    int r = blockIdx.x;
    int b = r >> 10, n = r & 1023;
    bool m1 = divided[(((size_t)b*Tc+0)*Nc+n)*3 + 0] > 0;
    const float* G = gsum + (size_t)r*H4c;
    for (int j = threadIdx.x; j < Hc; j += blockDim.x){
        float rg = sigmoid_f(G[j]);
        float zg = sigmoid_f(G[270+j]);
        float ng = tanhf(G[540+j] + rg*G[810+j]);
        float hv = (1.0f-zg)*ng;
        Abuf[(size_t)r*KAB + 32 + j] = m1 ? f2bf(hv) : (ushort_t)0;
    }
}

// ---------------------------------------------------------------------------
// out_last reduction (t=5), coalesced
// ---------------------------------------------------------------------------
__global__ __launch_bounds__(320)
void outlast_partial_kernel(const int* __restrict__ divided,
                            const float* __restrict__ hm1, const float* __restrict__ hm23,
                            float* __restrict__ part1, float* __restrict__ part23)
{
    int nc = blockIdx.x, b = blockIdx.y;
    int j = threadIdx.x;
    if (j >= Hc) return;
    float m1v = -INFINITY, m23v = -INFINITY;
    #pragma unroll 4
    for (int n = nc*32; n < nc*32+32; n++){
        const int* dv = divided + (((size_t)b*Tc + (Tc-1))*Nc + n)*3;
        bool m1  = dv[0] > 0;
        bool m23 = (dv[1] > 0) || (dv[2] > 0);
        size_t o = ((size_t)b*Nc+n)*Hc + j;
        if (m1)  m1v  = fmaxf(m1v,  hm1[o]);
        if (m23) m23v = fmaxf(m23v, hm23[o]);
    }
    part1 [((size_t)b*32+nc)*320 + j] = m1v;
    part23[((size_t)b*32+nc)*320 + j] = m23v;
}

__global__ __launch_bounds__(320)
void outlast_combine_kernel(const float* __restrict__ part1, const float* __restrict__ part23,
                            float* __restrict__ outlast)
{
    int b = blockIdx.x; int j = threadIdx.x;
    if (j >= Hc) return;
    float a = -INFINITY, c = -INFINITY;
    for (int nc=0;nc<32;nc++){
        a = fmaxf(a, part1 [((size_t)b*32+nc)*320 + j]);
        c = fmaxf(c, part23[((size_t)b*32+nc)*320 + j]);
    }
    outlast[(size_t)b*Hc + j] = (a==-INFINITY ? 0.0f : a) + (c==-INFINITY ? 0.0f : c);
}

// ---------------------------------------------------------------------------
// LSTM MFMA step: 68 blocks = 4 cellgroups(32) x 17 jgroups(16 j-cols)
// ---------------------------------------------------------------------------
__global__ __launch_bounds__(256)
void lstm_step_mfma(const float* __restrict__ gx,
                    const ushort_t* __restrict__ WhhRT,
                    const ushort_t* __restrict__ hb_in,
                    ushort_t* __restrict__ hb_out,
                    float* __restrict__ cst,
                    float* __restrict__ hev_out)
{
    int cg = blockIdx.x & 3, jg = blockIdx.x >> 2;
    int tid = threadIdx.x;
    int w = tid>>6, l = tid&63;
    int mi = w>>1, ni0 = (w&1)*2;
    int arow = cg*32 + mi*16 + (l&15);
    int koff = (l>>4)*8;
    const ushort_t* Wb = WhhRT + (size_t)jg*64*288;

    f4v acc0 = (f4v){0,0,0,0}, acc1 = (f4v){0,0,0,0};
    #pragma unroll
    for (int k0=0;k0<288;k0+=32){
        s8v a  = *(const s8v*)(hb_in + (size_t)arow*288 + k0 + koff);
        s8v b0 = *(const s8v*)(Wb + (size_t)(ni0*16 + (l&15))*288 + k0 + koff);
        s8v b1 = *(const s8v*)(Wb + (size_t)((ni0+1)*16 + (l&15))*288 + k0 + koff);
        acc0 = __builtin_amdgcn_mfma_f32_16x16x32_bf16(a, b0, acc0, 0,0,0);
        acc1 = __builtin_amdgcn_mfma_f32_16x16x32_bf16(a, b1, acc1, 0,0,0);
    }
    __shared__ float gs[32][64];
    int crow = mi*16 + (l>>4)*4;
    int ccol = l&15;
    #pragma unroll
    for (int r=0;r<4;r++){
        gs[crow+r][ni0*16 + ccol]     = acc0[r];
        gs[crow+r][(ni0+1)*16 + ccol] = acc1[r];
    }
    __syncthreads();
    #pragma unroll
    for (int p=0;p<2;p++){
        int idx = tid + p*256;
        int cl = idx>>4, jj = idx&15;
        int j = jg*16 + jj;
        if (j < Hc){
            int cell = cg*32 + cl;
            const float* g = gx + (size_t)cell*H4c;
            float ig = sigmoid_f(gs[cl][jj]      + g[j]);
            float fg = sigmoid_f(gs[cl][16+jj]   + g[Hc+j]);
            float gg = tanhf    (gs[cl][32+jj]   + g[2*Hc+j]);
            float og = sigmoid_f(gs[cl][48+jj]   + g[3*Hc+j]);
            size_t co = (size_t)cell*288 + j;
            float cn = fg*cst[co] + ig*gg;
            cst[co] = cn;
            float hn = og*tanhf(cn);
            hb_out[co] = f2bf(hn);
            if (hev_out) hev_out[(size_t)cell*Hc + j] = hn;
        }
    }
}

// ---------------------------------------------------------------------------
// heads: wdc + dp_attention over [outlast ; hev] -> o1 (o2 == o1)
// ---------------------------------------------------------------------------
__global__ __launch_bounds__(256)
void heads_kernel(const float* __restrict__ outlast, const float* __restrict__ hev,
                  const float* __restrict__ Wd, const float* __restrict__ bd,
                  const float* __restrict__ ctx, float* __restrict__ o1)
{
    int b = blockIdx.x, tid = threadIdx.x;
    __shared__ float wdc[Hc+1];
    __shared__ float sc[Ec+1];
    for (int j=tid;j<Hc;j+=256){
        float s = 0.0f;
        for (int d=0;d<DAc;d++) s += Wd[(size_t)j*DAc+d]*ctx[d];
        wdc[j] = s;
    }
    if (tid == 255){
        float s = 0.0f;
        for (int d=0;d<DAc;d++) s += bd[d]*ctx[d];
        wdc[Hc] = s;
    }
    __syncthreads();
    if (tid < Ec+1){
        const float* x = (tid==0) ? (outlast + (size_t)b*Hc)
                                  : (hev + ((size_t)b*Ec + tid-1)*Hc);
        float s = wdc[Hc];
        for (int j=0;j<Hc;j++) s += x[j]*wdc[j];
        sc[tid] = s;
    }
    __syncthreads();
    if (tid == 0){
        float m = -INFINITY;
        for (int s=0;s<Ec+1;s++) m = fmaxf(m, sc[s]);
        float sum = 0.0f;
        for (int s=0;s<Ec+1;s++){ sc[s] = expf(sc[s]-m); sum += sc[s]; }
        float inv = 1.0f/sum;
        for (int s=0;s<Ec+1;s++) sc[s] *= inv;
    }
    __syncthreads();
    for (int j=tid;j<Hc;j+=256){
        float acc = sc[0]*outlast[(size_t)b*Hc + j];
        for (int e=0;e<Ec;e++) acc += sc[1+e]*hev[((size_t)b*Ec+e)*Hc + j];
        o1[(size_t)b*Hc + j] = acc;
    }
}

// ---------------------------------------------------------------------------
extern "C" void kernel_launch(void* const* d_in, const int* in_sizes, int n_in,
                              void* d_out, int out_size, void* d_ws, size_t ws_size,
                              hipStream_t stream)
{
    const int*   code_x    = (const int*)d_in[0];
    const int*   divided   = (const int*)d_in[1];
    const int*   neighbors = (const int*)d_in[2];
    const int*   events    = (const int*)d_in[4];
    const float* c_emb     = (const float*)d_in[5];
    const float* n_emb     = (const float*)d_in[6];
    const float* u_emb     = (const float*)d_in[7];
    const float* adj       = (const float*)d_in[8];
    const float* Wg        = (const float*)d_in[9];
    const float* bg        = (const float*)d_in[10];
    const float* gru_Wih   = (const float*)d_in[11];
    const float* gru_Whh   = (const float*)d_in[12];
    const float* gru_bih   = (const float*)d_in[13];
    const float* gru_bhh   = (const float*)d_in[14];
    const float* Wq        = (const float*)d_in[15];
    const float* bq        = (const float*)d_in[16];
    const float* Wk        = (const float*)d_in[17];
    const float* bk        = (const float*)d_in[18];
    const float* Wv        = (const float*)d_in[19];
    const float* bv        = (const float*)d_in[20];
    const float* Wd        = (const float*)d_in[21];
    const float* bd        = (const float*)d_in[22];
    const float* ctx       = (const float*)d_in[23];
    const float* Eemb      = (const float*)d_in[24];
    const float* lstm_Wih  = (const float*)d_in[25];
    const float* lstm_Whh  = (const float*)d_in[26];
    const float* lstm_b    = (const float*)d_in[27];
    const float* Wc        = (const float*)d_in[28];
    const float* bc        = (const float*)d_in[29];
    float* out = (float*)d_out;

    float* ws = (float*)d_ws;
    size_t off = 0;
    auto alloc = [&](size_t n){ n = (n+7)&~(size_t)7; float* p = ws + off; off += n; return p; };
    auto allocU = [&](size_t n){ return (ushort_t*)alloc((n+1)/2); };

    float* hm1     = alloc((size_t)Bc*Nc*Hc);
    float* hm23    = alloc((size_t)Bc*Nc*Hc);
    float* S       = alloc((size_t)Nc*Bc*CSc);
    float* gsum    = alloc((size_t)Bc*Nc*H4c);          // also gatesx (lstm) alias
    ushort_t* Abuf  = allocU((size_t)Bc*Nc*KAB);        // [4096][320]: co | h | pad
    ushort_t* noA   = allocU((size_t)Bc*Nc*GSc);
    ushort_t* noB   = allocU((size_t)Bc*Nc*GSc);
    ushort_t* kSw   = allocU((size_t)Bc*Nc*ATc);        // swizzled K fragments
    ushort_t* vSw   = allocU((size_t)Bc*32*18*64*8);    // swizzled V fragments (incl pad)
    ushort_t* u_embb= allocU((size_t)Nc*GSc);
    ushort_t* WgT   = allocU((size_t)GSc*KPG);
    ushort_t* WB    = allocU((size_t)NCMB*KAB);
    ushort_t* WTl   = allocU((size_t)H4c*KPE);
    ushort_t* WhhRT = allocU((size_t)17*64*288);
    ushort_t* hbLA  = allocU((size_t)BEc*288);
    ushort_t* hbLB  = allocU((size_t)BEc*288);
    float* cst     = alloc((size_t)BEc*288);
    float* biasB   = alloc((size_t)NCMB);
    int*   nzc     = (int*)alloc((size_t)Nc);
    int*   nzidx   = (int*)alloc((size_t)Nc*NZCAP);
    float* outlast = alloc((size_t)Bc*Hc);
    float* o1      = alloc((size_t)Bc*Hc);
    float* hev     = alloc((size_t)BEc*Hc);
    float* part1   = alloc((size_t)Bc*32*320);
    float* part23  = alloc((size_t)Bc*32*320);

    float* gatesx  = gsum;     // lstm input gates alias (post-loop)
    (void)ws_size; (void)in_sizes; (void)n_in; (void)out_size;

    // ---- prep: conversions + zero fills; adj nz-lists ----
    {
        long long nb = (PRTOT + 255) / 256;
        prep_kernel<<<dim3((unsigned)nb), dim3(256), 0, stream>>>(
            u_emb, Wg, Wk, Wv, gru_Wih, gru_Whh, bk, bv, gru_bih, gru_bhh,
            lstm_Wih, lstm_Whh,
            u_embb, WgT, WB, biasB, WTl, WhhRT, hbLA, hbLB, cst, Abuf, vSw);
        nz_build_kernel<<<dim3(Nc), dim3(256), 0, stream>>>(adj, nzc, nzidx);
    }

    ushort_t* no_prev = noB;
    ushort_t* no_cur  = noA;
    for (int t=0; t<Tc; t++){
        s_sparse_kernel<<<dim3(Nc), dim3(192), 0, stream>>>(code_x, neighbors, c_emb, n_emb,
                                                            nzc, nzidx, t, S);
        // co|no = leaky((mask*(emb+S)) @ Wg + bg): dedicated VALU kernel
        cono_kernel<<<dim3(1024), dim3(256), 0, stream>>>(
            code_x, neighbors, c_emb, n_emb, S, Wg, bg, t, Abuf, no_cur);
        // combined k|v|gates = [co|h] @ WB + biasB  (k,v written pre-swizzled)
        mfma_k<5,0,0><<<dim3(11,32,1),256,0,stream>>>(
            Abuf, WB, biasB,
            kSw, vSw, gsum, nullptr, nullptr, nullptr,
            Bc*Nc, NCMB, KAB, KAB, KAB, 0, 0,0,0, 0);
        if (t == 0){
            gru_combine_t0_kernel<<<dim3(Bc*Nc), dim3(256), 0, stream>>>(gsum, divided, Abuf);
        } else {
            gru_combine_kernel<<<dim3(Bc*Nc), dim3(256), 0, stream>>>(gsum, Abuf, divided, hm1, t);
            // fused attention v4 (8 rows/block, 512 blocks)
            attn_fused_kernel<<<dim3(128, Bc), dim3(256), 0, stream>>>(
                no_prev, u_embb, Wq, bq, kSw, vSw, divided,
                Abuf, hm23, t, (t == Tc-1) ? 1 : 0);
            if (t == Tc-1){
                outlast_partial_kernel<<<dim3(32, Bc), dim3(320), 0, stream>>>(divided, hm1, hm23, part1, part23);
                outlast_combine_kernel<<<dim3(Bc), dim3(320), 0, stream>>>(part1, part23, outlast);
            }
        }
        ushort_t* tmp = no_prev; no_prev = no_cur; no_cur = tmp;
    }

    // ---- LSTM over last-visit events (gather fused into A-staging, ASEL3) ----
    mfma_k<0,0,3><<<dim3(9,32,1),256,0,stream>>>(
        nullptr, WTl, lstm_b,
        gatesx, nullptr, nullptr, Eemb, events, nullptr,
        BEc*Lc, H4c, KPE, 0, KPE, H4c, 0,0,0, 0);
    {
        ushort_t* hin = hbLA; ushort_t* hout = hbLB;
        for (int l=0; l<Lc; l++){
            lstm_step_mfma<<<dim3(68), dim3(256), 0, stream>>>(
                gatesx + (size_t)l*BEc*H4c, WhhRT, hin, hout, cst,
                (l == Lc-1) ? hev : nullptr);
            ushort_t* tmp = hin; hin = hout; hout = tmp;
        }
    }

    // ---- heads ----
    heads_kernel<<<dim3(Bc), dim3(256), 0, stream>>>(outlast, hev, Wd, bd, ctx, o1);
    {
        dim3 grid((OUTc+63)/64, 1, 1);
        gemm_kernel<3><<<grid,dim3(256),0,stream>>>(o1, Wc, bc, out, Bc, OUTc, Hc);
    }
}